// Round 7
// baseline (234.413 us; speedup 1.0000x reference)
//
#include <hip/hip_runtime.h>

#define B_ 4
#define S_ 1024
#define D_ 1024
#define H_ 16
#define DK_ 64

typedef __attribute__((ext_vector_type(8))) short short8;
typedef __attribute__((ext_vector_type(4))) float f32x4;
typedef __attribute__((ext_vector_type(16))) float f32x16;

// cbase[qb] (start chunk index per q-block), nch = (qb+2)>>1, packed bytes
#define CBASE_PACK 0x100C090604020100ULL

static __device__ __forceinline__ unsigned bf16rne(float x) {
    unsigned b = __float_as_uint(x);
    return (b + 0x7FFFu + ((b >> 16) & 1u)) >> 16;
}

// ---------------------------------------------------------------------------
// fp32 -> bf16 convert for q,k,v in one launch (outputs contiguous).
// ---------------------------------------------------------------------------
__global__ __launch_bounds__(256) void cvt3_bf16(
    const float* __restrict__ q, const float* __restrict__ k,
    const float* __restrict__ v, ushort* __restrict__ out)
{
    const size_t i = ((size_t)blockIdx.x * 256 + threadIdx.x) * 8;
    const size_t FM = (size_t)4 * 1024 * 1024;
    const float* in = (i < FM) ? q : (i < 2 * FM) ? k : v;
    const size_t off = i & (FM - 1);
    const float4 a = *reinterpret_cast<const float4*>(in + off);
    const float4 b = *reinterpret_cast<const float4*>(in + off + 4);
    union { ushort u[8]; int4 vv; } p;
    p.u[0] = (ushort)bf16rne(a.x); p.u[1] = (ushort)bf16rne(a.y);
    p.u[2] = (ushort)bf16rne(a.z); p.u[3] = (ushort)bf16rne(a.w);
    p.u[4] = (ushort)bf16rne(b.x); p.u[5] = (ushort)bf16rne(b.y);
    p.u[6] = (ushort)bf16rne(b.z); p.u[7] = (ushort)bf16rne(b.w);
    *reinterpret_cast<int4*>(out + i) = p.vv;
}

// ---------------------------------------------------------------------------
// W [1024][1024] fp32 -> Wt [n][k] bf16 (transpose + convert). z selects W.
// ---------------------------------------------------------------------------
__global__ __launch_bounds__(256) void transpose_cvt3(
    const float* __restrict__ W0, const float* __restrict__ W1,
    const float* __restrict__ W2, ushort* __restrict__ T0,
    ushort* __restrict__ T1, ushort* __restrict__ T2)
{
    __shared__ float ts[32][33];
    const float* W = (blockIdx.z == 0) ? W0 : (blockIdx.z == 1) ? W1 : W2;
    ushort*     Wt = (blockIdx.z == 0) ? T0 : (blockIdx.z == 1) ? T1 : T2;
    const int t  = threadIdx.x;
    const int k0 = blockIdx.y * 32, n0 = blockIdx.x * 32;
    const int r  = t >> 3, c4 = (t & 7) * 4;
    const float4 v = *reinterpret_cast<const float4*>(&W[(size_t)(k0 + r) * 1024 + n0 + c4]);
    ts[r][c4] = v.x; ts[r][c4 + 1] = v.y; ts[r][c4 + 2] = v.z; ts[r][c4 + 3] = v.w;
    __syncthreads();
    ushort4 o;
    o.x = (ushort)bf16rne(ts[c4    ][r]);
    o.y = (ushort)bf16rne(ts[c4 + 1][r]);
    o.z = (ushort)bf16rne(ts[c4 + 2][r]);
    o.w = (ushort)bf16rne(ts[c4 + 3][r]);
    *reinterpret_cast<ushort4*>(&Wt[(size_t)(n0 + r) * 1024 + k0 + c4]) = o;
}

// ---------------------------------------------------------------------------
// bf16 MFMA GEMM: C[M,1024] = X[M,1024] @ Wt^T (+bias, +resid).
// BM=64, BN=128, BK=64; 4 waves (2x2). 2-phase dbuf, counted vmcnt(6).
// MODE 0: fp32 + resid. MODE 1: merged QK bf16 headed (Q half pre-scaled
// by 1/8 for attention). MODE 2: bf16 [bh][DK][S].
// ---------------------------------------------------------------------------
template<int MODE>
__global__ __launch_bounds__(256) void gemm_mfma(
    const ushort* __restrict__ X, const ushort* __restrict__ Wt,
    const float* __restrict__ bias, const float* __restrict__ resid,
    void* __restrict__ out0, void* __restrict__ out1)
{
    __shared__ ushort As[2][64 * 64];
    __shared__ ushort Bs[2][128 * 64];

    const int t    = threadIdx.x;
    const int lane = t & 63;
    const int w    = t >> 6;

    const int cpx     = gridDim.x >> 3;
    const int logical = (blockIdx.x & 7) * cpx + (blockIdx.x >> 3);
    const int bm = logical >> 3;
    const int bn = logical & 7;

    const int srow   = lane >> 3;
    const int schunk = (lane & 7) ^ srow;
    const ushort* ag[2];
    const ushort* bg[4];
#pragma unroll
    for (int j = 0; j < 2; ++j)
        ag[j] = X  + (size_t)(bm * 64 + (j * 4 + w) * 8 + srow) * 1024 + schunk * 8;
#pragma unroll
    for (int j = 0; j < 4; ++j)
        bg[j] = Wt + (size_t)(bn * 128 + (j * 4 + w) * 8 + srow) * 1024 + schunk * 8;

#define STAGE(buf, k0)                                                           \
    do {                                                                         \
        _Pragma("unroll")                                                        \
        for (int j = 0; j < 2; ++j)                                              \
            __builtin_amdgcn_global_load_lds(                                    \
                (__attribute__((address_space(1))) const void*)(ag[j] + (k0)),   \
                (__attribute__((address_space(3))) void*)&As[buf][(j * 4 + w) * 512], \
                16, 0, 0);                                                       \
        _Pragma("unroll")                                                        \
        for (int j = 0; j < 4; ++j)                                              \
            __builtin_amdgcn_global_load_lds(                                    \
                (__attribute__((address_space(1))) const void*)(bg[j] + (k0)),   \
                (__attribute__((address_space(3))) void*)&Bs[buf][(j * 4 + w) * 512], \
                16, 0, 0);                                                       \
    } while (0)

    const int fr = lane & 15;
    const int fk = lane >> 4;
    const int wm = w >> 1, wn = w & 1;

    f32x4 acc[2][4];
#pragma unroll
    for (int m = 0; m < 2; ++m)
#pragma unroll
        for (int n = 0; n < 4; ++n) acc[m][n] = (f32x4){0.f, 0.f, 0.f, 0.f};

    STAGE(0, 0);
#pragma unroll 1
    for (int kt = 0; kt < 16; ++kt) {
        const int cur = kt & 1;
        if (kt + 1 < 16) {
            STAGE(cur ^ 1, (kt + 1) * 64);
            asm volatile("s_waitcnt vmcnt(6)" ::: "memory");
        } else {
            asm volatile("s_waitcnt vmcnt(0)" ::: "memory");
        }
        __builtin_amdgcn_s_barrier();
        __builtin_amdgcn_sched_barrier(0);
#pragma unroll
        for (int ks = 0; ks < 2; ++ks) {
            short8 af[2], bf[4];
#pragma unroll
            for (int m = 0; m < 2; ++m) {
                const int row = wm * 32 + m * 16 + fr;
                af[m] = *reinterpret_cast<const short8*>(
                    &As[cur][row * 64 + (((ks * 4 + fk) ^ (row & 7)) * 8)]);
            }
#pragma unroll
            for (int n = 0; n < 4; ++n) {
                const int row = wn * 64 + n * 16 + fr;
                bf[n] = *reinterpret_cast<const short8*>(
                    &Bs[cur][row * 64 + (((ks * 4 + fk) ^ (row & 7)) * 8)]);
            }
            __builtin_amdgcn_s_setprio(1);
#pragma unroll
            for (int m = 0; m < 2; ++m)
#pragma unroll
                for (int n = 0; n < 4; ++n)
                    acc[m][n] = __builtin_amdgcn_mfma_f32_16x16x32_bf16(
                        af[m], bf[n], acc[m][n], 0, 0, 0);
            __builtin_amdgcn_s_setprio(0);
        }
        __builtin_amdgcn_sched_barrier(0);
        __builtin_amdgcn_s_barrier();
        __builtin_amdgcn_sched_barrier(0);
    }
#undef STAGE

#pragma unroll
    for (int m = 0; m < 2; ++m) {
        const int row0 = bm * 64 + wm * 32 + m * 16 + fk * 4;
#pragma unroll
        for (int n = 0; n < 4; ++n) {
            const int col = bn * 128 + wn * 64 + n * 16 + fr;
            const float bc = bias[col];
            if (MODE == 0) {
                float* o = (float*)out0;
#pragma unroll
                for (int j = 0; j < 4; ++j) {
                    const int row = row0 + j;
                    o[(size_t)row * 1024 + col] =
                        acc[m][n][j] + bc + resid[(size_t)row * 1024 + col];
                }
            } else if (MODE == 1) {
                ushort* o = (row0 < 4096) ? (ushort*)out0 : (ushort*)out1;
                const float qs = (row0 < 4096) ? 0.125f : 1.0f;  // pre-scale Q by 1/sqrt(DK)
                const int r0 = row0 & 4095;
                const int b_ = r0 >> 10, s0 = r0 & 1023;
                const int h  = col >> 6,  dk = col & 63;
#pragma unroll
                for (int j = 0; j < 4; ++j)
                    o[(((size_t)b_ * H_ + h) * S_ + s0 + j) * DK_ + dk] =
                        (ushort)bf16rne((acc[m][n][j] + bc) * qs);
            } else {
                ushort* o = (ushort*)out0;
                const int b_ = row0 >> 10, s0 = row0 & 1023;
                const int h  = col >> 6,   dk = col & 63;
                ushort4 pk;
                pk.x = (ushort)bf16rne(acc[m][n][0] + bc);
                pk.y = (ushort)bf16rne(acc[m][n][1] + bc);
                pk.z = (ushort)bf16rne(acc[m][n][2] + bc);
                pk.w = (ushort)bf16rne(acc[m][n][3] + bc);
                *reinterpret_cast<ushort4*>(
                    &o[(((size_t)b_ * H_ + h) * DK_ + dk) * S_ + s0]) = pk;
            }
        }
    }
}

// ---------------------------------------------------------------------------
// MFMA bf16 flash attention v5: uniform 256-key chunks, SW register-prefetch
// one tile ahead (latency hidden under prev tile), b-adjacent block order for
// SW L2/L3 reuse, fragment-major LDS (0 conflicts), counted vmcnt dbuf.
// ---------------------------------------------------------------------------
__global__ __launch_bounds__(256, 3) void attn_mfma(
    const ushort* __restrict__ Qh, const ushort* __restrict__ Kh,
    const ushort* __restrict__ Vt, const float* __restrict__ SW,
    ushort* __restrict__ ctxP, float2* __restrict__ ml)
{
    __shared__ ushort Ks[2][4096];
    __shared__ ushort Vs[2][4096];

    const int t    = threadIdx.x;
    const int lane = t & 63;
    const int w    = t >> 6;
    // XCD-chunked; within a chunk, 4 consecutive blocks share (h,ci) across b
    // so their identical SW reads hit L2/L3.
    const int lg = (blockIdx.x & 7) * 160 + (blockIdx.x >> 3);
    const int b  = lg & 3;
    const int hc = lg >> 2;          // 0..319
    const int h  = hc / 20;
    const int ci = hc % 20;
    const int bh = b * 16 + h;
    int qb = 0;
#pragma unroll
    for (int q = 1; q < 8; ++q)
        if ((int)((CBASE_PACK >> (q * 8)) & 0xff) <= ci) qb = q;
    const int lc = ci - (int)((CBASE_PACK >> (qb * 8)) & 0xff);
    const int t0 = lc * 4;                         // first 64-key tile
    const int nt = min(4, 2 * qb + 2 - t0);        // 2 or 4 tiles (always even)

    const int ql = lane & 31;
    const int hi = lane >> 5;
    const int qrow = qb * 128 + ql * 4 + w;        // interleaved q-rows

    const ushort* Kg  = Kh + (size_t)bh * S_ * DK_;
    const ushort* Vg  = Vt + (size_t)bh * DK_ * S_;
    const float*  swp = SW + ((size_t)h * S_ + qrow) * S_;

    const ushort* kgp[2];
    const ushort* vgp[2];
#pragma unroll
    for (int j = 0; j < 2; ++j) {
        const int bb = w * 2 + j;
        const int g = bb >> 2, c = bb & 3;
        kgp[j] = Kg + (size_t)(g * 32 + ql) * DK_ + c * 16 + hi * 8;
        vgp[j] = Vg + (size_t)(g * 32 + ql) * S_  + c * 16 + hi * 8;
    }

#define ASTAGE(buf, k0)                                                          \
    do {                                                                         \
        _Pragma("unroll")                                                        \
        for (int j = 0; j < 2; ++j) {                                            \
            const int bb = w * 2 + j;                                            \
            __builtin_amdgcn_global_load_lds(                                    \
                (__attribute__((address_space(1))) const void*)(kgp[j] + (size_t)(k0) * DK_), \
                (__attribute__((address_space(3))) void*)&Ks[buf][bb * 512],     \
                16, 0, 0);                                                       \
            __builtin_amdgcn_global_load_lds(                                    \
                (__attribute__((address_space(1))) const void*)(vgp[j] + (k0)),  \
                (__attribute__((address_space(3))) void*)&Vs[buf][bb * 512],     \
                16, 0, 0);                                                       \
        }                                                                        \
    } while (0)

#define SWLOAD(dst, k0)                                                          \
    do {                                                                         \
        _Pragma("unroll")                                                        \
        for (int g2 = 0; g2 < 2; ++g2)                                           \
            _Pragma("unroll")                                                    \
            for (int j2 = 0; j2 < 4; ++j2)                                       \
                dst[g2 * 4 + j2] = *reinterpret_cast<const float4*>(             \
                    &swp[(k0) + g2 * 32 + hi * 4 + j2 * 8]);                     \
    } while (0)

    short8 qf[4];
    {
        const ushort* Qg = Qh + ((size_t)bh * S_ + qrow) * DK_;
#pragma unroll
        for (int c = 0; c < 4; ++c) {
            union { int4 i; short8 s; } u;
            u.i = *reinterpret_cast<const int4*>(&Qg[c * 16 + hi * 8]);
            qf[c] = u.s;
        }
    }

    f32x16 accA, accB;
#pragma unroll
    for (int r = 0; r < 16; ++r) { accA[r] = 0.f; accB[r] = 0.f; }
    float mrow = -1e30f, lrow = 0.f;

    float4 swA[8], swB[8];

    auto tile_body = [&](int ktt, int cur, const float4 (&swc)[8]) {
        const int k0 = (t0 + ktt) * 64;
        __builtin_amdgcn_s_barrier();
        __builtin_amdgcn_sched_barrier(0);

        // ---- QK^T (swapped), lane-linear frag reads ----
        f32x16 sc[2];
        __builtin_amdgcn_s_setprio(1);
#pragma unroll
        for (int g = 0; g < 2; ++g) {
#pragma unroll
            for (int r = 0; r < 16; ++r) sc[g][r] = 0.f;
#pragma unroll
            for (int c = 0; c < 4; ++c) {
                const short8 kf = *reinterpret_cast<const short8*>(
                    &Ks[cur][((g * 4 + c) * 64 + lane) * 8]);
                sc[g] = __builtin_amdgcn_mfma_f32_32x32x16_bf16(kf, qf[c], sc[g], 0, 0, 0);
            }
        }
        __builtin_amdgcn_s_setprio(0);

        // ---- scores (+SW) + online softmax; Q pre-scaled by 1/8 ----
        const bool masked = (t0 + ktt >= 2 * qb);
        float tmax = -1e30f;
        if (masked) {
#pragma unroll
            for (int g = 0; g < 2; ++g)
#pragma unroll
                for (int r = 0; r < 16; ++r) {
                    const int key = k0 + g * 32 + (r & 3) + ((r >> 2) << 3) + (hi << 2);
                    const float swv = ((const float*)&swc[g * 4 + (r >> 2)])[r & 3];
                    const float s = (key < qrow) ? sc[g][r] + swv : -1e30f;
                    sc[g][r] = s;
                    tmax = fmaxf(tmax, s);
                }
        } else {
#pragma unroll
            for (int g = 0; g < 2; ++g)
#pragma unroll
                for (int r = 0; r < 16; ++r) {
                    const float swv = ((const float*)&swc[g * 4 + (r >> 2)])[r & 3];
                    const float s = sc[g][r] + swv;
                    sc[g][r] = s;
                    tmax = fmaxf(tmax, s);
                }
        }
        tmax = fmaxf(tmax, __shfl_xor(tmax, 32, 64));
        const float mnew = fmaxf(mrow, tmax);
        const float corr = __expf(mrow - mnew);
        float psum = 0.f;
        if (masked) {
#pragma unroll
            for (int g = 0; g < 2; ++g)
#pragma unroll
                for (int r = 0; r < 16; ++r) {
                    const float e = (sc[g][r] > -1e29f) ? __expf(sc[g][r] - mnew) : 0.f;
                    sc[g][r] = e;
                    psum += e;
                }
        } else {
#pragma unroll
            for (int g = 0; g < 2; ++g)
#pragma unroll
                for (int r = 0; r < 16; ++r) {
                    const float e = __expf(sc[g][r] - mnew);
                    sc[g][r] = e;
                    psum += e;
                }
        }
        psum += __shfl_xor(psum, 32, 64);
        lrow = lrow * corr + psum;
        mrow = mnew;
#pragma unroll
        for (int r = 0; r < 16; ++r) { accA[r] *= corr; accB[r] *= corr; }

        // ---- P -> bf16 B-fragments (cvt_pk + cross-half exchange) ----
        short8 paf[4];
#pragma unroll
        for (int g = 0; g < 2; ++g) {
            unsigned pk[8];
#pragma unroll
            for (int j = 0; j < 8; ++j) {
                unsigned r_;
                asm("v_cvt_pk_bf16_f32 %0, %1, %2"
                    : "=v"(r_) : "v"(sc[g][2 * j]), "v"(sc[g][2 * j + 1]));
                pk[j] = r_;
            }
            unsigned x0 = (unsigned)__shfl_xor((int)pk[0], 32, 64);
            unsigned x1 = (unsigned)__shfl_xor((int)pk[1], 32, 64);
            unsigned x2 = (unsigned)__shfl_xor((int)pk[2], 32, 64);
            unsigned x3 = (unsigned)__shfl_xor((int)pk[3], 32, 64);
            unsigned x4 = (unsigned)__shfl_xor((int)pk[4], 32, 64);
            unsigned x5 = (unsigned)__shfl_xor((int)pk[5], 32, 64);
            unsigned x6 = (unsigned)__shfl_xor((int)pk[6], 32, 64);
            unsigned x7 = (unsigned)__shfl_xor((int)pk[7], 32, 64);
            union { unsigned u[4]; short8 s; } a0, a1;
            a0.u[0] = hi ? x2 : pk[0];
            a0.u[1] = hi ? x3 : pk[1];
            a0.u[2] = hi ? pk[2] : x0;
            a0.u[3] = hi ? pk[3] : x1;
            a1.u[0] = hi ? x6 : pk[4];
            a1.u[1] = hi ? x7 : pk[5];
            a1.u[2] = hi ? pk[6] : x4;
            a1.u[3] = hi ? pk[7] : x5;
            paf[g * 2 + 0] = a0.s;
            paf[g * 2 + 1] = a1.s;
        }

        // ---- PV (swapped), lane-linear frags ----
        __builtin_amdgcn_s_setprio(1);
#pragma unroll
        for (int cc = 0; cc < 4; ++cc) {
            const short8 va = *reinterpret_cast<const short8*>(
                &Vs[cur][((0 * 4 + cc) * 64 + lane) * 8]);
            const short8 vb = *reinterpret_cast<const short8*>(
                &Vs[cur][((1 * 4 + cc) * 64 + lane) * 8]);
            accA = __builtin_amdgcn_mfma_f32_32x32x16_bf16(va, paf[cc], accA, 0, 0, 0);
            accB = __builtin_amdgcn_mfma_f32_32x32x16_bf16(vb, paf[cc], accB, 0, 0, 0);
        }
        __builtin_amdgcn_s_setprio(0);

        __builtin_amdgcn_sched_barrier(0);
        __builtin_amdgcn_s_barrier();       // readers done before restage of cur
        __builtin_amdgcn_sched_barrier(0);
    };

    // prologue: SW(t0) + stage(t0)
    SWLOAD(swA, t0 * 64);
    ASTAGE(0, t0 * 64);

#pragma unroll 1
    for (int kt = 0; kt < nt; kt += 2) {
        // tile kt (buf 0, consume swA); prefetch SW+stage for kt+1 (buf 1)
        SWLOAD(swB, (t0 + kt + 1) * 64);
        ASTAGE(1, (t0 + kt + 1) * 64);
        asm volatile("s_waitcnt vmcnt(12)" ::: "memory");
        tile_body(kt, 0, swA);

        // tile kt+1 (buf 1, consume swB); prefetch SW+stage for kt+2 (buf 0)
        if (kt + 2 < nt) {
            SWLOAD(swA, (t0 + kt + 2) * 64);
            ASTAGE(0, (t0 + kt + 2) * 64);
            asm volatile("s_waitcnt vmcnt(12)" ::: "memory");
        } else {
            asm volatile("s_waitcnt vmcnt(0)" ::: "memory");
        }
        tile_body(kt + 1, 1, swB);
    }
#undef ASTAGE
#undef SWLOAD

    // ---- epilogue: normalized bf16 partial + (m,l) ----
    const float inv = (lrow > 0.f) ? 1.f / lrow : 0.f;
    ushort* crow_ = ctxP + ((size_t)(bh * 20 + ci) * 128 + (ql * 4 + w)) * 64;
#pragma unroll
    for (int g = 0; g < 4; ++g) {
        ushort4 oA, oB;
        oA.x = (ushort)bf16rne(accA[4 * g + 0] * inv);
        oA.y = (ushort)bf16rne(accA[4 * g + 1] * inv);
        oA.z = (ushort)bf16rne(accA[4 * g + 2] * inv);
        oA.w = (ushort)bf16rne(accA[4 * g + 3] * inv);
        oB.x = (ushort)bf16rne(accB[4 * g + 0] * inv);
        oB.y = (ushort)bf16rne(accB[4 * g + 1] * inv);
        oB.z = (ushort)bf16rne(accB[4 * g + 2] * inv);
        oB.w = (ushort)bf16rne(accB[4 * g + 3] * inv);
        *reinterpret_cast<ushort4*>(&crow_[g * 8 + hi * 4])      = oA;
        *reinterpret_cast<ushort4*>(&crow_[g * 8 + hi * 4 + 32]) = oB;
    }
    if (hi == 0) {
        float2 v; v.x = mrow; v.y = lrow;
        ml[(size_t)(bh * 20 + ci) * 128 + ql * 4 + w] = v;
    }
}

// ---------------------------------------------------------------------------
// Merge chunk partials (1..4 per q-row): out = sum_c w_c * o_c.
// ---------------------------------------------------------------------------
__global__ __launch_bounds__(256) void attn_merge(
    const ushort* __restrict__ ctxP, const float2* __restrict__ ml,
    ushort* __restrict__ ctx)
{
    const size_t idx = ((size_t)blockIdx.x * 256 + threadIdx.x) * 8;
    const int col = (int)(idx & 1023);
    const int row = (int)(idx >> 10);
    const int b = row >> 10, s = row & 1023;
    const int h = col >> 6, dk0 = col & 63;
    const int bh = b * 16 + h;
    const int qb = s >> 7, rl = s & 127;
    const int nch = (qb + 2) >> 1;
    const int cb  = (int)((CBASE_PACK >> (qb * 8)) & 0xff);

    float mm[4], ll[4];
    float m = -1e30f;
#pragma unroll
    for (int c = 0; c < 4; ++c)
        if (c < nch) {
            const float2 v = ml[(size_t)(bh * 20 + cb + c) * 128 + rl];
            mm[c] = v.x; ll[c] = v.y;
            m = fmaxf(m, v.x);
        }
    float wc[4], wsum = 0.f;
#pragma unroll
    for (int c = 0; c < 4; ++c)
        if (c < nch) { wc[c] = ll[c] * __expf(mm[c] - m); wsum += wc[c]; }
    const float inv = (wsum > 0.f) ? 1.f / wsum : 0.f;

    float o[8] = {0.f, 0.f, 0.f, 0.f, 0.f, 0.f, 0.f, 0.f};
#pragma unroll
    for (int c = 0; c < 4; ++c)
        if (c < nch) {
            union { int4 v; ushort u[8]; } p;
            p.v = *reinterpret_cast<const int4*>(
                &ctxP[((size_t)(bh * 20 + cb + c) * 128 + rl) * 64 + dk0]);
            const float wgt = wc[c] * inv;
#pragma unroll
            for (int i = 0; i < 8; ++i)
                o[i] += wgt * __uint_as_float((unsigned)p.u[i] << 16);
        }
    union { int4 v; ushort u[8]; } r;
#pragma unroll
    for (int i = 0; i < 8; ++i) r.u[i] = (ushort)bf16rne(o[i]);
    *reinterpret_cast<int4*>(ctx + idx) = r.v;
}

// ---------------------------------------------------------------------------
// LayerNorm over last dim (1024).
// ---------------------------------------------------------------------------
__global__ __launch_bounds__(256) void layernorm_k(
    const float* __restrict__ x, const float* __restrict__ gamma,
    const float* __restrict__ beta, float* __restrict__ out)
{
    const int row = blockIdx.x;
    const int t   = threadIdx.x;
    const float4 v = *reinterpret_cast<const float4*>(&x[(size_t)row * D_ + (t << 2)]);
    float sum = v.x + v.y + v.z + v.w;
    float sq  = v.x * v.x + v.y * v.y + v.z * v.z + v.w * v.w;
#pragma unroll
    for (int w = 1; w < 64; w <<= 1) {
        sum += __shfl_xor(sum, w, 64);
        sq  += __shfl_xor(sq,  w, 64);
    }
    __shared__ float red[8];
    const int wid = t >> 6;
    if ((t & 63) == 0) { red[wid] = sum; red[wid + 4] = sq; }
    __syncthreads();
    sum = red[0] + red[1] + red[2] + red[3];
    sq  = red[4] + red[5] + red[6] + red[7];
    const float mu  = sum * (1.f / 1024.f);
    const float var = sq * (1.f / 1024.f) - mu * mu;
    const float rs  = rsqrtf(var + 1e-5f);
    const float4 gm = *reinterpret_cast<const float4*>(&gamma[t << 2]);
    const float4 bt = *reinterpret_cast<const float4*>(&beta[t << 2]);
    float4 o;
    o.x = (v.x - mu) * rs * gm.x + bt.x;
    o.y = (v.y - mu) * rs * gm.y + bt.y;
    o.z = (v.z - mu) * rs * gm.z + bt.z;
    o.w = (v.w - mu) * rs * gm.w + bt.w;
    *reinterpret_cast<float4*>(&out[(size_t)row * D_ + (t << 2)]) = o;
}

// ---------------------------------------------------------------------------
extern "C" void kernel_launch(void* const* d_in, const int* in_sizes, int n_in,
                              void* d_out, int out_size, void* d_ws, size_t ws_size,
                              hipStream_t stream)
{
    const float* query  = (const float*)d_in[0];
    const float* key    = (const float*)d_in[1];
    const float* values = (const float*)d_in[2];
    const float* SW     = (const float*)d_in[4];
    const float* Wq     = (const float*)d_in[5];
    const float* bq     = (const float*)d_in[6];
    const float* Wv     = (const float*)d_in[7];
    const float* bv     = (const float*)d_in[8];
    const float* Wo     = (const float*)d_in[9];
    const float* bo     = (const float*)d_in[10];
    const float* gamma  = (const float*)d_in[11];
    const float* beta   = (const float*)d_in[12];

    char* ws = (char*)d_ws;
    const size_t MB = 1024 * 1024;
    ushort* Qh   = (ushort*)(ws);              //  8 MB bf16 [bh][S][DK] (pre-scaled 1/8)
    ushort* Kh   = (ushort*)(ws +  8 * MB);
    ushort* Vt   = (ushort*)(ws + 16 * MB);    //  8 MB bf16 [bh][DK][S]
    ushort* Wqt  = (ushort*)(ws + 24 * MB);
    ushort* Wvt  = (ushort*)(ws + 26 * MB);
    ushort* Wot  = (ushort*)(ws + 28 * MB);
    ushort* qbf  = (ushort*)(ws + 30 * MB);    //  8 MB (qbf|kbf contiguous for QK gemm)
    ushort* kbf  = (ushort*)(ws + 38 * MB);
    ushort* vbf  = (ushort*)(ws + 46 * MB);
    float2* ml   = (float2*)(ws + 54 * MB);    //  1.3 MB
    ushort* ctxP = qbf;                        // 21 MB partials, overlays 30-51
    ushort* ctxm = Qh;                         //  8 MB merged, overlays Qh
    float*  xbf  = (float*)(ws + 8 * MB);      // 16 MB fp32, overlays Kh|Vt

    const dim3 blk(256);

    cvt3_bf16<<<dim3(6144), blk, 0, stream>>>(query, key, values, qbf);
    transpose_cvt3<<<dim3(32, 32, 3), blk, 0, stream>>>(Wq, Wv, Wo, Wqt, Wvt, Wot);

    gemm_mfma<1><<<dim3(1024), blk, 0, stream>>>(qbf, Wqt, bq, nullptr, Qh, Kh);
    gemm_mfma<2><<<dim3(512),  blk, 0, stream>>>(vbf, Wvt, bv, nullptr, Vt, nullptr);

    attn_mfma<<<dim3(1280), blk, 0, stream>>>(Qh, Kh, Vt, SW, ctxP, ml);
    attn_merge<<<dim3(2048), blk, 0, stream>>>(ctxP, ml, ctxm);

    gemm_mfma<0><<<dim3(512), blk, 0, stream>>>(ctxm, Wot, bo, query, xbf, nullptr);

    layernorm_k<<<dim3(4096), blk, 0, stream>>>(xbf, gamma, beta, (float*)d_out);
}

// Round 8
// 165.856 us; speedup vs baseline: 1.4134x; 1.4134x over previous
//
#include <hip/hip_runtime.h>

#define B_ 4
#define S_ 1024
#define D_ 1024
#define H_ 16
#define DK_ 64

typedef __attribute__((ext_vector_type(8))) short short8;
typedef __attribute__((ext_vector_type(4))) float f32x4;
typedef __attribute__((ext_vector_type(16))) float f32x16;

// cbase[qb] (start chunk index per q-block), nch = (qb+2)>>1, packed bytes
#define CBASE_PACK 0x100C090604020100ULL

static __device__ __forceinline__ unsigned bf16rne(float x) {
    unsigned b = __float_as_uint(x);
    return (b + 0x7FFFu + ((b >> 16) & 1u)) >> 16;
}

// ---------------------------------------------------------------------------
// fp32 -> bf16 convert for q,k,v in one launch (outputs contiguous).
// ---------------------------------------------------------------------------
__global__ __launch_bounds__(256) void cvt3_bf16(
    const float* __restrict__ q, const float* __restrict__ k,
    const float* __restrict__ v, ushort* __restrict__ out)
{
    const size_t i = ((size_t)blockIdx.x * 256 + threadIdx.x) * 8;
    const size_t FM = (size_t)4 * 1024 * 1024;
    const float* in = (i < FM) ? q : (i < 2 * FM) ? k : v;
    const size_t off = i & (FM - 1);
    const float4 a = *reinterpret_cast<const float4*>(in + off);
    const float4 b = *reinterpret_cast<const float4*>(in + off + 4);
    union { ushort u[8]; int4 vv; } p;
    p.u[0] = (ushort)bf16rne(a.x); p.u[1] = (ushort)bf16rne(a.y);
    p.u[2] = (ushort)bf16rne(a.z); p.u[3] = (ushort)bf16rne(a.w);
    p.u[4] = (ushort)bf16rne(b.x); p.u[5] = (ushort)bf16rne(b.y);
    p.u[6] = (ushort)bf16rne(b.z); p.u[7] = (ushort)bf16rne(b.w);
    *reinterpret_cast<int4*>(out + i) = p.vv;
}

// ---------------------------------------------------------------------------
// W [1024][1024] fp32 -> Wt [n][k] bf16 (transpose + convert). z selects W.
// ---------------------------------------------------------------------------
__global__ __launch_bounds__(256) void transpose_cvt3(
    const float* __restrict__ W0, const float* __restrict__ W1,
    const float* __restrict__ W2, ushort* __restrict__ T0,
    ushort* __restrict__ T1, ushort* __restrict__ T2)
{
    __shared__ float ts[32][33];
    const float* W = (blockIdx.z == 0) ? W0 : (blockIdx.z == 1) ? W1 : W2;
    ushort*     Wt = (blockIdx.z == 0) ? T0 : (blockIdx.z == 1) ? T1 : T2;
    const int t  = threadIdx.x;
    const int k0 = blockIdx.y * 32, n0 = blockIdx.x * 32;
    const int r  = t >> 3, c4 = (t & 7) * 4;
    const float4 v = *reinterpret_cast<const float4*>(&W[(size_t)(k0 + r) * 1024 + n0 + c4]);
    ts[r][c4] = v.x; ts[r][c4 + 1] = v.y; ts[r][c4 + 2] = v.z; ts[r][c4 + 3] = v.w;
    __syncthreads();
    ushort4 o;
    o.x = (ushort)bf16rne(ts[c4    ][r]);
    o.y = (ushort)bf16rne(ts[c4 + 1][r]);
    o.z = (ushort)bf16rne(ts[c4 + 2][r]);
    o.w = (ushort)bf16rne(ts[c4 + 3][r]);
    *reinterpret_cast<ushort4*>(&Wt[(size_t)(n0 + r) * 1024 + k0 + c4]) = o;
}

// ---------------------------------------------------------------------------
// bf16 MFMA GEMM: C[M,1024] = X[M,1024] @ Wt^T (+bias, +resid).
// BM=64, BN=128, BK=64; 4 waves (2x2). 2-phase dbuf, counted vmcnt(6).
// MODE 0: fp32 + resid. MODE 1: merged QK bf16 headed (Q half pre-scaled
// by 1/8 for attention). MODE 2: bf16 [bh][DK][S].
// ---------------------------------------------------------------------------
template<int MODE>
__global__ __launch_bounds__(256) void gemm_mfma(
    const ushort* __restrict__ X, const ushort* __restrict__ Wt,
    const float* __restrict__ bias, const float* __restrict__ resid,
    void* __restrict__ out0, void* __restrict__ out1)
{
    __shared__ ushort As[2][64 * 64];
    __shared__ ushort Bs[2][128 * 64];

    const int t    = threadIdx.x;
    const int lane = t & 63;
    const int w    = t >> 6;

    const int cpx     = gridDim.x >> 3;
    const int logical = (blockIdx.x & 7) * cpx + (blockIdx.x >> 3);
    const int bm = logical >> 3;
    const int bn = logical & 7;

    const int srow   = lane >> 3;
    const int schunk = (lane & 7) ^ srow;
    const ushort* ag[2];
    const ushort* bg[4];
#pragma unroll
    for (int j = 0; j < 2; ++j)
        ag[j] = X  + (size_t)(bm * 64 + (j * 4 + w) * 8 + srow) * 1024 + schunk * 8;
#pragma unroll
    for (int j = 0; j < 4; ++j)
        bg[j] = Wt + (size_t)(bn * 128 + (j * 4 + w) * 8 + srow) * 1024 + schunk * 8;

#define STAGE(buf, k0)                                                           \
    do {                                                                         \
        _Pragma("unroll")                                                        \
        for (int j = 0; j < 2; ++j)                                              \
            __builtin_amdgcn_global_load_lds(                                    \
                (__attribute__((address_space(1))) const void*)(ag[j] + (k0)),   \
                (__attribute__((address_space(3))) void*)&As[buf][(j * 4 + w) * 512], \
                16, 0, 0);                                                       \
        _Pragma("unroll")                                                        \
        for (int j = 0; j < 4; ++j)                                              \
            __builtin_amdgcn_global_load_lds(                                    \
                (__attribute__((address_space(1))) const void*)(bg[j] + (k0)),   \
                (__attribute__((address_space(3))) void*)&Bs[buf][(j * 4 + w) * 512], \
                16, 0, 0);                                                       \
    } while (0)

    const int fr = lane & 15;
    const int fk = lane >> 4;
    const int wm = w >> 1, wn = w & 1;

    f32x4 acc[2][4];
#pragma unroll
    for (int m = 0; m < 2; ++m)
#pragma unroll
        for (int n = 0; n < 4; ++n) acc[m][n] = (f32x4){0.f, 0.f, 0.f, 0.f};

    STAGE(0, 0);
#pragma unroll 1
    for (int kt = 0; kt < 16; ++kt) {
        const int cur = kt & 1;
        if (kt + 1 < 16) {
            STAGE(cur ^ 1, (kt + 1) * 64);
            asm volatile("s_waitcnt vmcnt(6)" ::: "memory");
        } else {
            asm volatile("s_waitcnt vmcnt(0)" ::: "memory");
        }
        __builtin_amdgcn_s_barrier();
        __builtin_amdgcn_sched_barrier(0);
#pragma unroll
        for (int ks = 0; ks < 2; ++ks) {
            short8 af[2], bf[4];
#pragma unroll
            for (int m = 0; m < 2; ++m) {
                const int row = wm * 32 + m * 16 + fr;
                af[m] = *reinterpret_cast<const short8*>(
                    &As[cur][row * 64 + (((ks * 4 + fk) ^ (row & 7)) * 8)]);
            }
#pragma unroll
            for (int n = 0; n < 4; ++n) {
                const int row = wn * 64 + n * 16 + fr;
                bf[n] = *reinterpret_cast<const short8*>(
                    &Bs[cur][row * 64 + (((ks * 4 + fk) ^ (row & 7)) * 8)]);
            }
            __builtin_amdgcn_s_setprio(1);
#pragma unroll
            for (int m = 0; m < 2; ++m)
#pragma unroll
                for (int n = 0; n < 4; ++n)
                    acc[m][n] = __builtin_amdgcn_mfma_f32_16x16x32_bf16(
                        af[m], bf[n], acc[m][n], 0, 0, 0);
            __builtin_amdgcn_s_setprio(0);
        }
        __builtin_amdgcn_sched_barrier(0);
        __builtin_amdgcn_s_barrier();
        __builtin_amdgcn_sched_barrier(0);
    }
#undef STAGE

#pragma unroll
    for (int m = 0; m < 2; ++m) {
        const int row0 = bm * 64 + wm * 32 + m * 16 + fk * 4;
#pragma unroll
        for (int n = 0; n < 4; ++n) {
            const int col = bn * 128 + wn * 64 + n * 16 + fr;
            const float bc = bias[col];
            if (MODE == 0) {
                float* o = (float*)out0;
#pragma unroll
                for (int j = 0; j < 4; ++j) {
                    const int row = row0 + j;
                    o[(size_t)row * 1024 + col] =
                        acc[m][n][j] + bc + resid[(size_t)row * 1024 + col];
                }
            } else if (MODE == 1) {
                ushort* o = (row0 < 4096) ? (ushort*)out0 : (ushort*)out1;
                const float qs = (row0 < 4096) ? 0.125f : 1.0f;  // pre-scale Q by 1/sqrt(DK)
                const int r0 = row0 & 4095;
                const int b_ = r0 >> 10, s0 = r0 & 1023;
                const int h  = col >> 6,  dk = col & 63;
#pragma unroll
                for (int j = 0; j < 4; ++j)
                    o[(((size_t)b_ * H_ + h) * S_ + s0 + j) * DK_ + dk] =
                        (ushort)bf16rne((acc[m][n][j] + bc) * qs);
            } else {
                ushort* o = (ushort*)out0;
                const int b_ = row0 >> 10, s0 = row0 & 1023;
                const int h  = col >> 6,   dk = col & 63;
                ushort4 pk;
                pk.x = (ushort)bf16rne(acc[m][n][0] + bc);
                pk.y = (ushort)bf16rne(acc[m][n][1] + bc);
                pk.z = (ushort)bf16rne(acc[m][n][2] + bc);
                pk.w = (ushort)bf16rne(acc[m][n][3] + bc);
                *reinterpret_cast<ushort4*>(
                    &o[(((size_t)b_ * H_ + h) * DK_ + dk) * S_ + s0]) = pk;
            }
        }
    }
}

// ---------------------------------------------------------------------------
// MFMA bf16 flash attention v6: barrier-free, LDS-free. Each wave is an
// independent stream over its 256-key chunk: K/V tiles loaded straight to
// VGPR fragments, SW double-buffered in registers (named sets, literal
// indices only -- no spills), SW folded into the QK MFMA accumulator init.
// ---------------------------------------------------------------------------
__global__ __launch_bounds__(256) void attn_mfma(
    const ushort* __restrict__ Qh, const ushort* __restrict__ Kh,
    const ushort* __restrict__ Vt, const float* __restrict__ SW,
    ushort* __restrict__ ctxP, float2* __restrict__ ml)
{
    const int t    = threadIdx.x;
    const int lane = t & 63;
    const int w    = t >> 6;
    // XCD-chunked; 4 consecutive blocks share (h,ci) across b for SW L2 reuse.
    const int lg = (blockIdx.x & 7) * 160 + (blockIdx.x >> 3);
    const int b  = lg & 3;
    const int hc = lg >> 2;          // 0..319
    const int h  = hc / 20;
    const int ci = hc % 20;
    const int bh = b * 16 + h;
    int qb = 0;
#pragma unroll
    for (int q = 1; q < 8; ++q)
        if ((int)((CBASE_PACK >> (q * 8)) & 0xff) <= ci) qb = q;
    const int lc = ci - (int)((CBASE_PACK >> (qb * 8)) & 0xff);
    const int t0 = lc * 4;                         // first 64-key tile
    const int nt = min(4, 2 * qb + 2 - t0);        // 2 or 4 tiles (always even)

    const int ql = lane & 31;
    const int hi = lane >> 5;
    const int qrow = qb * 128 + ql * 4 + w;        // interleaved q-rows

    const ushort* Kg  = Kh + (size_t)bh * S_ * DK_;
    const ushort* Vg  = Vt + (size_t)bh * DK_ * S_;
    const float*  swp = SW + ((size_t)h * S_ + qrow) * S_;

    // Q B-fragments (Q pre-scaled by 1/8 in projection)
    short8 qf[4];
    {
        const ushort* Qg = Qh + ((size_t)bh * S_ + qrow) * DK_;
#pragma unroll
        for (int c = 0; c < 4; ++c) {
            union { int4 i; short8 s; } u;
            u.i = *reinterpret_cast<const int4*>(&Qg[c * 16 + hi * 8]);
            qf[c] = u.s;
        }
    }

    f32x16 accA, accB;
#pragma unroll
    for (int r = 0; r < 16; ++r) { accA[r] = 0.f; accB[r] = 0.f; }
    float mrow = -1e30f, lrow = 0.f;

    int4 kA[8];          // K tile fragments (reloaded in place each tile)
    int4 vv[8];          // V^T tile fragments
    float4 sA[8], sB[8]; // SW double buffer

#define LOADK(kt_)                                                               \
    do {                                                                         \
        const size_t kb_ = (size_t)(t0 + (kt_)) * 64 * DK_;                      \
        _Pragma("unroll")                                                        \
        for (int j = 0; j < 8; ++j)                                              \
            kA[j] = *reinterpret_cast<const int4*>(                              \
                &Kg[kb_ + (size_t)((j >> 2) * 32 + ql) * DK_ + (j & 3) * 16 + hi * 8]); \
    } while (0)

#define LOADV(kt_)                                                               \
    do {                                                                         \
        const int kv_ = (t0 + (kt_)) * 64;                                       \
        _Pragma("unroll")                                                        \
        for (int j = 0; j < 8; ++j)                                              \
            vv[j] = *reinterpret_cast<const int4*>(                              \
                &Vg[(size_t)((j >> 2) * 32 + ql) * S_ + kv_ + (j & 3) * 16 + hi * 8]); \
    } while (0)

#define LOADS(dst, kt_)                                                          \
    do {                                                                         \
        const int ks_ = (t0 + (kt_)) * 64;                                       \
        _Pragma("unroll")                                                        \
        for (int j = 0; j < 8; ++j)                                              \
            dst[j] = *reinterpret_cast<const float4*>(                           \
                &swp[ks_ + (j >> 2) * 32 + hi * 4 + (j & 3) * 8]);               \
    } while (0)

#define BODY(CURS, NXTS, ktt)                                                    \
    do {                                                                         \
        const int k0_ = (t0 + (ktt)) * 64;                                       \
        LOADV(ktt);                                                              \
        /* QK^T with SW as accumulator init (Q pre-scaled) */                    \
        f32x16 sc0, sc1;                                                         \
        _Pragma("unroll")                                                        \
        for (int r = 0; r < 16; ++r) {                                           \
            sc0[r] = ((const float*)&CURS[(r >> 2)])[r & 3];                     \
            sc1[r] = ((const float*)&CURS[4 + (r >> 2)])[r & 3];                 \
        }                                                                        \
        _Pragma("unroll")                                                        \
        for (int c = 0; c < 4; ++c) {                                            \
            union { int4 i; short8 s; } k0u, k1u;                                \
            k0u.i = kA[c];  k1u.i = kA[4 + c];                                   \
            sc0 = __builtin_amdgcn_mfma_f32_32x32x16_bf16(k0u.s, qf[c], sc0, 0, 0, 0); \
            sc1 = __builtin_amdgcn_mfma_f32_32x32x16_bf16(k1u.s, qf[c], sc1, 0, 0, 0); \
        }                                                                        \
        /* prefetch next tile's K and SW (kA dead after QK) */                   \
        if ((ktt) + 1 < nt) { LOADK((ktt) + 1); LOADS(NXTS, (ktt) + 1); }        \
        /* mask (diagonal tiles only) + online softmax */                        \
        float tmax = -1e30f;                                                     \
        if (t0 + (ktt) >= 2 * qb) {                                              \
            _Pragma("unroll")                                                    \
            for (int r = 0; r < 16; ++r) {                                       \
                const int key0 = k0_ + (r & 3) + ((r >> 2) << 3) + (hi << 2);    \
                if (key0 >= qrow)      sc0[r] = -1e30f;                          \
                if (key0 + 32 >= qrow) sc1[r] = -1e30f;                          \
                tmax = fmaxf(tmax, fmaxf(sc0[r], sc1[r]));                       \
            }                                                                    \
        } else {                                                                 \
            _Pragma("unroll")                                                    \
            for (int r = 0; r < 16; ++r)                                         \
                tmax = fmaxf(tmax, fmaxf(sc0[r], sc1[r]));                       \
        }                                                                        \
        tmax = fmaxf(tmax, __shfl_xor(tmax, 32, 64));                            \
        const float mnew = fmaxf(mrow, tmax);                                    \
        const float corr = __expf(mrow - mnew);                                  \
        float psum = 0.f;                                                        \
        _Pragma("unroll")                                                        \
        for (int r = 0; r < 16; ++r) {                                           \
            const float e0 = (sc0[r] > -1e29f) ? __expf(sc0[r] - mnew) : 0.f;    \
            const float e1 = (sc1[r] > -1e29f) ? __expf(sc1[r] - mnew) : 0.f;    \
            sc0[r] = e0; sc1[r] = e1;                                            \
            psum += e0 + e1;                                                     \
        }                                                                        \
        psum += __shfl_xor(psum, 32, 64);                                        \
        lrow = lrow * corr + psum;                                               \
        mrow = mnew;                                                             \
        _Pragma("unroll")                                                        \
        for (int r = 0; r < 16; ++r) { accA[r] *= corr; accB[r] *= corr; }       \
        /* P -> bf16 B-fragments (cvt_pk + cross-half exchange) */               \
        short8 paf[4];                                                           \
        _Pragma("unroll")                                                        \
        for (int g = 0; g < 2; ++g) {                                            \
            unsigned pk[8];                                                      \
            _Pragma("unroll")                                                    \
            for (int j = 0; j < 8; ++j) {                                        \
                unsigned r_;                                                     \
                const float lo_ = g ? sc1[2 * j]     : sc0[2 * j];               \
                const float hi_ = g ? sc1[2 * j + 1] : sc0[2 * j + 1];           \
                asm("v_cvt_pk_bf16_f32 %0, %1, %2" : "=v"(r_) : "v"(lo_), "v"(hi_)); \
                pk[j] = r_;                                                      \
            }                                                                    \
            unsigned x0 = (unsigned)__shfl_xor((int)pk[0], 32, 64);              \
            unsigned x1 = (unsigned)__shfl_xor((int)pk[1], 32, 64);              \
            unsigned x2 = (unsigned)__shfl_xor((int)pk[2], 32, 64);              \
            unsigned x3 = (unsigned)__shfl_xor((int)pk[3], 32, 64);              \
            unsigned x4 = (unsigned)__shfl_xor((int)pk[4], 32, 64);              \
            unsigned x5 = (unsigned)__shfl_xor((int)pk[5], 32, 64);              \
            unsigned x6 = (unsigned)__shfl_xor((int)pk[6], 32, 64);              \
            unsigned x7 = (unsigned)__shfl_xor((int)pk[7], 32, 64);              \
            union { unsigned u[4]; short8 s; } a0, a1;                           \
            a0.u[0] = hi ? x2 : pk[0];                                           \
            a0.u[1] = hi ? x3 : pk[1];                                           \
            a0.u[2] = hi ? pk[2] : x0;                                           \
            a0.u[3] = hi ? pk[3] : x1;                                           \
            a1.u[0] = hi ? x6 : pk[4];                                           \
            a1.u[1] = hi ? x7 : pk[5];                                           \
            a1.u[2] = hi ? pk[6] : x4;                                           \
            a1.u[3] = hi ? pk[7] : x5;                                           \
            paf[g * 2 + 0] = a0.s;                                               \
            paf[g * 2 + 1] = a1.s;                                               \
        }                                                                        \
        /* PV from V^T register fragments */                                     \
        _Pragma("unroll")                                                        \
        for (int cc = 0; cc < 4; ++cc) {                                         \
            union { int4 i; short8 s; } va, vb;                                  \
            va.i = vv[cc]; vb.i = vv[4 + cc];                                    \
            accA = __builtin_amdgcn_mfma_f32_32x32x16_bf16(va.s, paf[cc], accA, 0, 0, 0); \
            accB = __builtin_amdgcn_mfma_f32_32x32x16_bf16(vb.s, paf[cc], accB, 0, 0, 0); \
        }                                                                        \
    } while (0)

    LOADK(0);
    LOADS(sA, 0);
#pragma unroll 1
    for (int kt = 0; kt < nt; kt += 2) {
        BODY(sA, sB, kt);
        BODY(sB, sA, kt + 1);
    }
#undef LOADK
#undef LOADV
#undef LOADS
#undef BODY

    // ---- epilogue: normalized bf16 partial + (m,l) ----
    const float inv = (lrow > 0.f) ? 1.f / lrow : 0.f;
    ushort* crow_ = ctxP + ((size_t)(bh * 20 + ci) * 128 + (ql * 4 + w)) * 64;
#pragma unroll
    for (int g = 0; g < 4; ++g) {
        ushort4 oA, oB;
        oA.x = (ushort)bf16rne(accA[4 * g + 0] * inv);
        oA.y = (ushort)bf16rne(accA[4 * g + 1] * inv);
        oA.z = (ushort)bf16rne(accA[4 * g + 2] * inv);
        oA.w = (ushort)bf16rne(accA[4 * g + 3] * inv);
        oB.x = (ushort)bf16rne(accB[4 * g + 0] * inv);
        oB.y = (ushort)bf16rne(accB[4 * g + 1] * inv);
        oB.z = (ushort)bf16rne(accB[4 * g + 2] * inv);
        oB.w = (ushort)bf16rne(accB[4 * g + 3] * inv);
        *reinterpret_cast<ushort4*>(&crow_[g * 8 + hi * 4])      = oA;
        *reinterpret_cast<ushort4*>(&crow_[g * 8 + hi * 4 + 32]) = oB;
    }
    if (hi == 0) {
        float2 v; v.x = mrow; v.y = lrow;
        ml[(size_t)(bh * 20 + ci) * 128 + ql * 4 + w] = v;
    }
}

// ---------------------------------------------------------------------------
// Merge chunk partials (1..4 per q-row): out = sum_c w_c * o_c.
// ---------------------------------------------------------------------------
__global__ __launch_bounds__(256) void attn_merge(
    const ushort* __restrict__ ctxP, const float2* __restrict__ ml,
    ushort* __restrict__ ctx)
{
    const size_t idx = ((size_t)blockIdx.x * 256 + threadIdx.x) * 8;
    const int col = (int)(idx & 1023);
    const int row = (int)(idx >> 10);
    const int b = row >> 10, s = row & 1023;
    const int h = col >> 6, dk0 = col & 63;
    const int bh = b * 16 + h;
    const int qb = s >> 7, rl = s & 127;
    const int nch = (qb + 2) >> 1;
    const int cb  = (int)((CBASE_PACK >> (qb * 8)) & 0xff);

    float mm[4], ll[4];
    float m = -1e30f;
#pragma unroll
    for (int c = 0; c < 4; ++c)
        if (c < nch) {
            const float2 v = ml[(size_t)(bh * 20 + cb + c) * 128 + rl];
            mm[c] = v.x; ll[c] = v.y;
            m = fmaxf(m, v.x);
        }
    float wc[4], wsum = 0.f;
#pragma unroll
    for (int c = 0; c < 4; ++c)
        if (c < nch) { wc[c] = ll[c] * __expf(mm[c] - m); wsum += wc[c]; }
    const float inv = (wsum > 0.f) ? 1.f / wsum : 0.f;

    float o[8] = {0.f, 0.f, 0.f, 0.f, 0.f, 0.f, 0.f, 0.f};
#pragma unroll
    for (int c = 0; c < 4; ++c)
        if (c < nch) {
            union { int4 v; ushort u[8]; } p;
            p.v = *reinterpret_cast<const int4*>(
                &ctxP[((size_t)(bh * 20 + cb + c) * 128 + rl) * 64 + dk0]);
            const float wgt = wc[c] * inv;
#pragma unroll
            for (int i = 0; i < 8; ++i)
                o[i] += wgt * __uint_as_float((unsigned)p.u[i] << 16);
        }
    union { int4 v; ushort u[8]; } r;
#pragma unroll
    for (int i = 0; i < 8; ++i) r.u[i] = (ushort)bf16rne(o[i]);
    *reinterpret_cast<int4*>(ctx + idx) = r.v;
}

// ---------------------------------------------------------------------------
// LayerNorm over last dim (1024).
// ---------------------------------------------------------------------------
__global__ __launch_bounds__(256) void layernorm_k(
    const float* __restrict__ x, const float* __restrict__ gamma,
    const float* __restrict__ beta, float* __restrict__ out)
{
    const int row = blockIdx.x;
    const int t   = threadIdx.x;
    const float4 v = *reinterpret_cast<const float4*>(&x[(size_t)row * D_ + (t << 2)]);
    float sum = v.x + v.y + v.z + v.w;
    float sq  = v.x * v.x + v.y * v.y + v.z * v.z + v.w * v.w;
#pragma unroll
    for (int w = 1; w < 64; w <<= 1) {
        sum += __shfl_xor(sum, w, 64);
        sq  += __shfl_xor(sq,  w, 64);
    }
    __shared__ float red[8];
    const int wid = t >> 6;
    if ((t & 63) == 0) { red[wid] = sum; red[wid + 4] = sq; }
    __syncthreads();
    sum = red[0] + red[1] + red[2] + red[3];
    sq  = red[4] + red[5] + red[6] + red[7];
    const float mu  = sum * (1.f / 1024.f);
    const float var = sq * (1.f / 1024.f) - mu * mu;
    const float rs  = rsqrtf(var + 1e-5f);
    const float4 gm = *reinterpret_cast<const float4*>(&gamma[t << 2]);
    const float4 bt = *reinterpret_cast<const float4*>(&beta[t << 2]);
    float4 o;
    o.x = (v.x - mu) * rs * gm.x + bt.x;
    o.y = (v.y - mu) * rs * gm.y + bt.y;
    o.z = (v.z - mu) * rs * gm.z + bt.z;
    o.w = (v.w - mu) * rs * gm.w + bt.w;
    *reinterpret_cast<float4*>(&out[(size_t)row * D_ + (t << 2)]) = o;
}

// ---------------------------------------------------------------------------
extern "C" void kernel_launch(void* const* d_in, const int* in_sizes, int n_in,
                              void* d_out, int out_size, void* d_ws, size_t ws_size,
                              hipStream_t stream)
{
    const float* query  = (const float*)d_in[0];
    const float* key    = (const float*)d_in[1];
    const float* values = (const float*)d_in[2];
    const float* SW     = (const float*)d_in[4];
    const float* Wq     = (const float*)d_in[5];
    const float* bq     = (const float*)d_in[6];
    const float* Wv     = (const float*)d_in[7];
    const float* bv     = (const float*)d_in[8];
    const float* Wo     = (const float*)d_in[9];
    const float* bo     = (const float*)d_in[10];
    const float* gamma  = (const float*)d_in[11];
    const float* beta   = (const float*)d_in[12];

    char* ws = (char*)d_ws;
    const size_t MB = 1024 * 1024;
    ushort* Qh   = (ushort*)(ws);              //  8 MB bf16 [bh][S][DK] (pre-scaled 1/8)
    ushort* Kh   = (ushort*)(ws +  8 * MB);
    ushort* Vt   = (ushort*)(ws + 16 * MB);    //  8 MB bf16 [bh][DK][S]
    ushort* Wqt  = (ushort*)(ws + 24 * MB);
    ushort* Wvt  = (ushort*)(ws + 26 * MB);
    ushort* Wot  = (ushort*)(ws + 28 * MB);
    ushort* qbf  = (ushort*)(ws + 30 * MB);    //  8 MB (qbf|kbf contiguous for QK gemm)
    ushort* kbf  = (ushort*)(ws + 38 * MB);
    ushort* vbf  = (ushort*)(ws + 46 * MB);
    float2* ml   = (float2*)(ws + 54 * MB);    //  1.3 MB
    ushort* ctxP = qbf;                        // 21 MB partials, overlays 30-51
    ushort* ctxm = Qh;                         //  8 MB merged, overlays Qh
    float*  xbf  = (float*)(ws + 8 * MB);      // 16 MB fp32, overlays Kh|Vt

    const dim3 blk(256);

    cvt3_bf16<<<dim3(6144), blk, 0, stream>>>(query, key, values, qbf);
    transpose_cvt3<<<dim3(32, 32, 3), blk, 0, stream>>>(Wq, Wv, Wo, Wqt, Wvt, Wot);

    gemm_mfma<1><<<dim3(1024), blk, 0, stream>>>(qbf, Wqt, bq, nullptr, Qh, Kh);
    gemm_mfma<2><<<dim3(512),  blk, 0, stream>>>(vbf, Wvt, bv, nullptr, Vt, nullptr);

    attn_mfma<<<dim3(1280), blk, 0, stream>>>(Qh, Kh, Vt, SW, ctxP, ml);
    attn_merge<<<dim3(2048), blk, 0, stream>>>(ctxP, ml, ctxm);

    gemm_mfma<0><<<dim3(512), blk, 0, stream>>>(ctxm, Wot, bo, query, xbf, nullptr);

    layernorm_k<<<dim3(4096), blk, 0, stream>>>(xbf, gamma, beta, (float*)d_out);
}

// Round 9
// 144.983 us; speedup vs baseline: 1.6168x; 1.1440x over previous
//
#include <hip/hip_runtime.h>

#define B_ 4
#define S_ 1024
#define D_ 1024
#define H_ 16
#define DK_ 64

typedef __attribute__((ext_vector_type(8))) short short8;
typedef __attribute__((ext_vector_type(4))) float f32x4;
typedef __attribute__((ext_vector_type(16))) float f32x16;

// cbase[qb] (start chunk index per q-block), nch = (qb+2)>>1, packed bytes
#define CBASE_PACK 0x100C090604020100ULL

static __device__ __forceinline__ unsigned bf16rne(float x) {
    unsigned b = __float_as_uint(x);
    return (b + 0x7FFFu + ((b >> 16) & 1u)) >> 16;
}

// ---------------------------------------------------------------------------
// W [1024][1024] fp32 -> Wt [n][k] bf16 (transpose + convert). z selects W.
// ---------------------------------------------------------------------------
__global__ __launch_bounds__(256) void transpose_cvt3(
    const float* __restrict__ W0, const float* __restrict__ W1,
    const float* __restrict__ W2, ushort* __restrict__ T0,
    ushort* __restrict__ T1, ushort* __restrict__ T2)
{
    __shared__ float ts[32][33];
    const float* W = (blockIdx.z == 0) ? W0 : (blockIdx.z == 1) ? W1 : W2;
    ushort*     Wt = (blockIdx.z == 0) ? T0 : (blockIdx.z == 1) ? T1 : T2;
    const int t  = threadIdx.x;
    const int k0 = blockIdx.y * 32, n0 = blockIdx.x * 32;
    const int r  = t >> 3, c4 = (t & 7) * 4;
    const float4 v = *reinterpret_cast<const float4*>(&W[(size_t)(k0 + r) * 1024 + n0 + c4]);
    ts[r][c4] = v.x; ts[r][c4 + 1] = v.y; ts[r][c4 + 2] = v.z; ts[r][c4 + 3] = v.w;
    __syncthreads();
    ushort4 o;
    o.x = (ushort)bf16rne(ts[c4    ][r]);
    o.y = (ushort)bf16rne(ts[c4 + 1][r]);
    o.z = (ushort)bf16rne(ts[c4 + 2][r]);
    o.w = (ushort)bf16rne(ts[c4 + 3][r]);
    *reinterpret_cast<ushort4*>(&Wt[(size_t)(n0 + r) * 1024 + k0 + c4]) = o;
}

// ---------------------------------------------------------------------------
// bf16 MFMA GEMM with fp32 A fused conversion:
// C[M,1024] = cvt_bf16(Xf)[M,1024] @ Wt^T + bias. BM=64, BN=128, BK=64.
// A: reg-staged (float4 loads -> cvt_pk -> ds_write_b128), B: global_load_lds.
// Counted vmcnt so A-loads hide under MFMA. MODE 1: merged QK (rows<4096 from
// Xf0 -> out0 with 1/8 pre-scale; rows>=4096 from Xf1 -> out1), bf16
// [bh][S][DK]. MODE 2: bf16 [bh][DK][S].
// ---------------------------------------------------------------------------
template<int MODE>
__global__ __launch_bounds__(256) void gemm_f32a(
    const float* __restrict__ Xf0, const float* __restrict__ Xf1,
    const ushort* __restrict__ Wt, const float* __restrict__ bias,
    void* __restrict__ out0, void* __restrict__ out1)
{
    __shared__ ushort As[2][64 * 64];
    __shared__ ushort Bs[2][128 * 64];

    const int t    = threadIdx.x;
    const int lane = t & 63;
    const int w    = t >> 6;

    const int cpx     = gridDim.x >> 3;
    const int logical = (blockIdx.x & 7) * cpx + (blockIdx.x >> 3);
    const int bm = logical >> 3;
    const int bn = logical & 7;

    const int srow   = lane >> 3;
    const int schunk = (lane & 7) ^ srow;

    const float* Xf = (MODE == 1 && bm >= 64) ? Xf1 : Xf0;
    const int rbase = (bm * 64) & 4095;
    const float* ap[2];
#pragma unroll
    for (int j = 0; j < 2; ++j)
        ap[j] = Xf + (size_t)(rbase + (j * 4 + w) * 8 + srow) * 1024 + schunk * 8;

    const ushort* bg[4];
#pragma unroll
    for (int j = 0; j < 4; ++j)
        bg[j] = Wt + (size_t)(bn * 128 + (j * 4 + w) * 8 + srow) * 1024 + schunk * 8;

    float4 aRx0, aRy0, aRx1, aRy1;

#define A_ISSUE(k0)                                                              \
    do {                                                                         \
        aRx0 = *reinterpret_cast<const float4*>(ap[0] + (k0));                   \
        aRy0 = *reinterpret_cast<const float4*>(ap[0] + (k0) + 4);               \
        aRx1 = *reinterpret_cast<const float4*>(ap[1] + (k0));                   \
        aRy1 = *reinterpret_cast<const float4*>(ap[1] + (k0) + 4);               \
    } while (0)

#define B_STAGE(buf, k0)                                                         \
    do {                                                                         \
        _Pragma("unroll")                                                        \
        for (int j = 0; j < 4; ++j)                                              \
            __builtin_amdgcn_global_load_lds(                                    \
                (__attribute__((address_space(1))) const void*)(bg[j] + (k0)),   \
                (__attribute__((address_space(3))) void*)&Bs[buf][(j * 4 + w) * 512], \
                16, 0, 0);                                                       \
    } while (0)

#define A_WRITE(buf)                                                             \
    do {                                                                         \
        union { unsigned u[4]; int4 v; } p0, p1;                                 \
        asm("v_cvt_pk_bf16_f32 %0, %1, %2" : "=v"(p0.u[0]) : "v"(aRx0.x), "v"(aRx0.y)); \
        asm("v_cvt_pk_bf16_f32 %0, %1, %2" : "=v"(p0.u[1]) : "v"(aRx0.z), "v"(aRx0.w)); \
        asm("v_cvt_pk_bf16_f32 %0, %1, %2" : "=v"(p0.u[2]) : "v"(aRy0.x), "v"(aRy0.y)); \
        asm("v_cvt_pk_bf16_f32 %0, %1, %2" : "=v"(p0.u[3]) : "v"(aRy0.z), "v"(aRy0.w)); \
        asm("v_cvt_pk_bf16_f32 %0, %1, %2" : "=v"(p1.u[0]) : "v"(aRx1.x), "v"(aRx1.y)); \
        asm("v_cvt_pk_bf16_f32 %0, %1, %2" : "=v"(p1.u[1]) : "v"(aRx1.z), "v"(aRx1.w)); \
        asm("v_cvt_pk_bf16_f32 %0, %1, %2" : "=v"(p1.u[2]) : "v"(aRy1.x), "v"(aRy1.y)); \
        asm("v_cvt_pk_bf16_f32 %0, %1, %2" : "=v"(p1.u[3]) : "v"(aRy1.z), "v"(aRy1.w)); \
        *reinterpret_cast<int4*>(&As[buf][((0 * 4 + w) * 64 + lane) * 8]) = p0.v; \
        *reinterpret_cast<int4*>(&As[buf][((1 * 4 + w) * 64 + lane) * 8]) = p1.v; \
    } while (0)

    const int fr = lane & 15;
    const int fk = lane >> 4;
    const int wm = w >> 1, wn = w & 1;

    f32x4 acc[2][4];
#pragma unroll
    for (int m = 0; m < 2; ++m)
#pragma unroll
        for (int n = 0; n < 4; ++n) acc[m][n] = (f32x4){0.f, 0.f, 0.f, 0.f};

    // prologue: tile 0
    A_ISSUE(0);
    B_STAGE(0, 0);
    asm volatile("s_waitcnt vmcnt(4)" ::: "memory");   // A regs ready
    A_WRITE(0);
    asm volatile("s_waitcnt lgkmcnt(0)" ::: "memory");

#pragma unroll 1
    for (int kt = 0; kt < 16; ++kt) {
        const int cur = kt & 1;
        if (kt + 1 < 16) {
            A_ISSUE((kt + 1) * 64);
            B_STAGE(cur ^ 1, (kt + 1) * 64);
            asm volatile("s_waitcnt vmcnt(8)" ::: "memory");  // cur tile's B landed
        } else {
            asm volatile("s_waitcnt vmcnt(0)" ::: "memory");
        }
        __builtin_amdgcn_s_barrier();
        __builtin_amdgcn_sched_barrier(0);
#pragma unroll
        for (int ks = 0; ks < 2; ++ks) {
            short8 af[2], bf[4];
#pragma unroll
            for (int m = 0; m < 2; ++m) {
                const int row = wm * 32 + m * 16 + fr;
                af[m] = *reinterpret_cast<const short8*>(
                    &As[cur][row * 64 + (((ks * 4 + fk) ^ (row & 7)) * 8)]);
            }
#pragma unroll
            for (int n = 0; n < 4; ++n) {
                const int row = wn * 64 + n * 16 + fr;
                bf[n] = *reinterpret_cast<const short8*>(
                    &Bs[cur][row * 64 + (((ks * 4 + fk) ^ (row & 7)) * 8)]);
            }
            __builtin_amdgcn_s_setprio(1);
#pragma unroll
            for (int m = 0; m < 2; ++m)
#pragma unroll
                for (int n = 0; n < 4; ++n)
                    acc[m][n] = __builtin_amdgcn_mfma_f32_16x16x32_bf16(
                        af[m], bf[n], acc[m][n], 0, 0, 0);
            __builtin_amdgcn_s_setprio(0);
        }
        if (kt + 1 < 16) {
            asm volatile("s_waitcnt vmcnt(4)" ::: "memory");  // next A regs ready
            A_WRITE(cur ^ 1);
            asm volatile("s_waitcnt lgkmcnt(0)" ::: "memory");
        }
        __builtin_amdgcn_sched_barrier(0);
        __builtin_amdgcn_s_barrier();
        __builtin_amdgcn_sched_barrier(0);
    }
#undef A_ISSUE
#undef B_STAGE
#undef A_WRITE

#pragma unroll
    for (int m = 0; m < 2; ++m) {
        const int row0 = bm * 64 + wm * 32 + m * 16 + fk * 4;
#pragma unroll
        for (int n = 0; n < 4; ++n) {
            const int col = bn * 128 + wn * 64 + n * 16 + fr;
            const float bc = bias[col];
            if (MODE == 1) {
                ushort* o = (row0 < 4096) ? (ushort*)out0 : (ushort*)out1;
                const float qs = (row0 < 4096) ? 0.125f : 1.0f;  // pre-scale Q
                const int r0 = row0 & 4095;
                const int b_ = r0 >> 10, s0 = r0 & 1023;
                const int h  = col >> 6,  dk = col & 63;
#pragma unroll
                for (int j = 0; j < 4; ++j)
                    o[(((size_t)b_ * H_ + h) * S_ + s0 + j) * DK_ + dk] =
                        (ushort)bf16rne((acc[m][n][j] + bc) * qs);
            } else {
                ushort* o = (ushort*)out0;
                const int b_ = row0 >> 10, s0 = row0 & 1023;
                const int h  = col >> 6,   dk = col & 63;
                ushort4 pk;
                pk.x = (ushort)bf16rne(acc[m][n][0] + bc);
                pk.y = (ushort)bf16rne(acc[m][n][1] + bc);
                pk.z = (ushort)bf16rne(acc[m][n][2] + bc);
                pk.w = (ushort)bf16rne(acc[m][n][3] + bc);
                *reinterpret_cast<ushort4*>(
                    &o[(((size_t)b_ * H_ + h) * DK_ + dk) * S_ + s0]) = pk;
            }
        }
    }
}

// ---------------------------------------------------------------------------
// bf16-A MFMA GEMM (output projection): C = ctx @ Wt^T + bias + resid (fp32).
// Proven R8 structure: 2-phase dbuf, global_load_lds A+B, counted vmcnt(6).
// ---------------------------------------------------------------------------
__global__ __launch_bounds__(256) void gemm_bf16a(
    const ushort* __restrict__ X, const ushort* __restrict__ Wt,
    const float* __restrict__ bias, const float* __restrict__ resid,
    float* __restrict__ out)
{
    __shared__ ushort As[2][64 * 64];
    __shared__ ushort Bs[2][128 * 64];

    const int t    = threadIdx.x;
    const int lane = t & 63;
    const int w    = t >> 6;

    const int cpx     = gridDim.x >> 3;
    const int logical = (blockIdx.x & 7) * cpx + (blockIdx.x >> 3);
    const int bm = logical >> 3;
    const int bn = logical & 7;

    const int srow   = lane >> 3;
    const int schunk = (lane & 7) ^ srow;
    const ushort* ag[2];
    const ushort* bg[4];
#pragma unroll
    for (int j = 0; j < 2; ++j)
        ag[j] = X  + (size_t)(bm * 64 + (j * 4 + w) * 8 + srow) * 1024 + schunk * 8;
#pragma unroll
    for (int j = 0; j < 4; ++j)
        bg[j] = Wt + (size_t)(bn * 128 + (j * 4 + w) * 8 + srow) * 1024 + schunk * 8;

#define STAGE(buf, k0)                                                           \
    do {                                                                         \
        _Pragma("unroll")                                                        \
        for (int j = 0; j < 2; ++j)                                              \
            __builtin_amdgcn_global_load_lds(                                    \
                (__attribute__((address_space(1))) const void*)(ag[j] + (k0)),   \
                (__attribute__((address_space(3))) void*)&As[buf][(j * 4 + w) * 512], \
                16, 0, 0);                                                       \
        _Pragma("unroll")                                                        \
        for (int j = 0; j < 4; ++j)                                              \
            __builtin_amdgcn_global_load_lds(                                    \
                (__attribute__((address_space(1))) const void*)(bg[j] + (k0)),   \
                (__attribute__((address_space(3))) void*)&Bs[buf][(j * 4 + w) * 512], \
                16, 0, 0);                                                       \
    } while (0)

    const int fr = lane & 15;
    const int fk = lane >> 4;
    const int wm = w >> 1, wn = w & 1;

    f32x4 acc[2][4];
#pragma unroll
    for (int m = 0; m < 2; ++m)
#pragma unroll
        for (int n = 0; n < 4; ++n) acc[m][n] = (f32x4){0.f, 0.f, 0.f, 0.f};

    STAGE(0, 0);
#pragma unroll 1
    for (int kt = 0; kt < 16; ++kt) {
        const int cur = kt & 1;
        if (kt + 1 < 16) {
            STAGE(cur ^ 1, (kt + 1) * 64);
            asm volatile("s_waitcnt vmcnt(6)" ::: "memory");
        } else {
            asm volatile("s_waitcnt vmcnt(0)" ::: "memory");
        }
        __builtin_amdgcn_s_barrier();
        __builtin_amdgcn_sched_barrier(0);
#pragma unroll
        for (int ks = 0; ks < 2; ++ks) {
            short8 af[2], bf[4];
#pragma unroll
            for (int m = 0; m < 2; ++m) {
                const int row = wm * 32 + m * 16 + fr;
                af[m] = *reinterpret_cast<const short8*>(
                    &As[cur][row * 64 + (((ks * 4 + fk) ^ (row & 7)) * 8)]);
            }
#pragma unroll
            for (int n = 0; n < 4; ++n) {
                const int row = wn * 64 + n * 16 + fr;
                bf[n] = *reinterpret_cast<const short8*>(
                    &Bs[cur][row * 64 + (((ks * 4 + fk) ^ (row & 7)) * 8)]);
            }
            __builtin_amdgcn_s_setprio(1);
#pragma unroll
            for (int m = 0; m < 2; ++m)
#pragma unroll
                for (int n = 0; n < 4; ++n)
                    acc[m][n] = __builtin_amdgcn_mfma_f32_16x16x32_bf16(
                        af[m], bf[n], acc[m][n], 0, 0, 0);
            __builtin_amdgcn_s_setprio(0);
        }
        __builtin_amdgcn_sched_barrier(0);
        __builtin_amdgcn_s_barrier();
        __builtin_amdgcn_sched_barrier(0);
    }
#undef STAGE

#pragma unroll
    for (int m = 0; m < 2; ++m) {
        const int row0 = bm * 64 + wm * 32 + m * 16 + fk * 4;
#pragma unroll
        for (int n = 0; n < 4; ++n) {
            const int col = bn * 128 + wn * 64 + n * 16 + fr;
            const float bc = bias[col];
#pragma unroll
            for (int j = 0; j < 4; ++j) {
                const int row = row0 + j;
                out[(size_t)row * 1024 + col] =
                    acc[m][n][j] + bc + resid[(size_t)row * 1024 + col];
            }
        }
    }
}

// ---------------------------------------------------------------------------
// MFMA bf16 flash attention v7 = R6 structure (LDS dbuf, shared tiles,
// counted vmcnt, uniform 256-key chunks) + R8 block ordering (b in low bits
// -> SW L2/L3 reuse, FETCH ~31MB) + pre-scaled Q + SW gathers issued at tile
// top (latency hides under QK MFMAs).
// ---------------------------------------------------------------------------
__global__ __launch_bounds__(256) void attn_mfma(
    const ushort* __restrict__ Qh, const ushort* __restrict__ Kh,
    const ushort* __restrict__ Vt, const float* __restrict__ SW,
    ushort* __restrict__ ctxP, float2* __restrict__ ml)
{
    __shared__ ushort Ks[2][4096];
    __shared__ ushort Vs[2][4096];

    const int t    = threadIdx.x;
    const int lane = t & 63;
    const int w    = t >> 6;
    // XCD-chunked; 4 consecutive blocks share (h,ci) across b -> SW L2 reuse.
    const int lg = (blockIdx.x & 7) * 160 + (blockIdx.x >> 3);
    const int b  = lg & 3;
    const int hc = lg >> 2;          // 0..319
    const int h  = hc / 20;
    const int ci = hc % 20;
    const int bh = b * 16 + h;
    int qb = 0;
#pragma unroll
    for (int q = 1; q < 8; ++q)
        if ((int)((CBASE_PACK >> (q * 8)) & 0xff) <= ci) qb = q;
    const int lc = ci - (int)((CBASE_PACK >> (qb * 8)) & 0xff);
    const int t0 = lc * 4;                         // first 64-key tile
    const int nt = min(4, 2 * qb + 2 - t0);        // 2 or 4 tiles

    const int ql = lane & 31;
    const int hi = lane >> 5;
    const int qrow = qb * 128 + ql * 4 + w;        // interleaved q-rows

    const ushort* Kg  = Kh + (size_t)bh * S_ * DK_;
    const ushort* Vg  = Vt + (size_t)bh * DK_ * S_;
    const float*  swp = SW + ((size_t)h * S_ + qrow) * S_;

    const ushort* kgp[2];
    const ushort* vgp[2];
#pragma unroll
    for (int j = 0; j < 2; ++j) {
        const int bb = w * 2 + j;
        const int g = bb >> 2, c = bb & 3;
        kgp[j] = Kg + (size_t)(g * 32 + ql) * DK_ + c * 16 + hi * 8;
        vgp[j] = Vg + (size_t)(g * 32 + ql) * S_  + c * 16 + hi * 8;
    }

#define ASTAGE(buf, k0)                                                          \
    do {                                                                         \
        _Pragma("unroll")                                                        \
        for (int j = 0; j < 2; ++j) {                                            \
            const int bb = w * 2 + j;                                            \
            __builtin_amdgcn_global_load_lds(                                    \
                (__attribute__((address_space(1))) const void*)(kgp[j] + (size_t)(k0) * DK_), \
                (__attribute__((address_space(3))) void*)&Ks[buf][bb * 512],     \
                16, 0, 0);                                                       \
            __builtin_amdgcn_global_load_lds(                                    \
                (__attribute__((address_space(1))) const void*)(vgp[j] + (k0)),  \
                (__attribute__((address_space(3))) void*)&Vs[buf][bb * 512],     \
                16, 0, 0);                                                       \
        }                                                                        \
    } while (0)

    // Q B-fragments (pre-scaled by 1/8 in projection)
    short8 qf[4];
    {
        const ushort* Qg = Qh + ((size_t)bh * S_ + qrow) * DK_;
#pragma unroll
        for (int c = 0; c < 4; ++c) {
            union { int4 i; short8 s; } u;
            u.i = *reinterpret_cast<const int4*>(&Qg[c * 16 + hi * 8]);
            qf[c] = u.s;
        }
    }

    f32x16 accA, accB;
#pragma unroll
    for (int r = 0; r < 16; ++r) { accA[r] = 0.f; accB[r] = 0.f; }
    float mrow = -1e30f, lrow = 0.f;

    ASTAGE(0, t0 * 64);

#pragma unroll 1
    for (int kt = 0; kt < nt; ++kt) {
        const int cur = kt & 1;
        const int k0  = (t0 + kt) * 64;
        if (kt + 1 < nt) {
            ASTAGE(cur ^ 1, (t0 + kt + 1) * 64);
            asm volatile("s_waitcnt vmcnt(4)" ::: "memory");
        } else {
            asm volatile("s_waitcnt vmcnt(0)" ::: "memory");
        }
        __builtin_amdgcn_s_barrier();
        __builtin_amdgcn_sched_barrier(0);

        // ---- state_weight gathers first: latency hides under QK MFMAs ----
        float swv[2][16];
#pragma unroll
        for (int g = 0; g < 2; ++g)
#pragma unroll
            for (int j = 0; j < 4; ++j) {
                const float4 v = *reinterpret_cast<const float4*>(
                    &swp[k0 + g * 32 + hi * 4 + j * 8]);
                swv[g][j * 4 + 0] = v.x; swv[g][j * 4 + 1] = v.y;
                swv[g][j * 4 + 2] = v.z; swv[g][j * 4 + 3] = v.w;
            }

        // ---- QK^T (swapped), lane-linear frag reads ----
        f32x16 sc[2];
        __builtin_amdgcn_s_setprio(1);
#pragma unroll
        for (int g = 0; g < 2; ++g) {
#pragma unroll
            for (int r = 0; r < 16; ++r) sc[g][r] = 0.f;
#pragma unroll
            for (int c = 0; c < 4; ++c) {
                const short8 kf = *reinterpret_cast<const short8*>(
                    &Ks[cur][((g * 4 + c) * 64 + lane) * 8]);
                sc[g] = __builtin_amdgcn_mfma_f32_32x32x16_bf16(kf, qf[c], sc[g], 0, 0, 0);
            }
        }
        __builtin_amdgcn_s_setprio(0);

        // ---- scores + online softmax (Q pre-scaled; SW additive) ----
        float pr[2][16];
        float tmax = -1e30f;
        if (t0 + kt >= 2 * qb) {     // masked (diagonal) tile
#pragma unroll
            for (int g = 0; g < 2; ++g)
#pragma unroll
                for (int r = 0; r < 16; ++r) {
                    const int key = k0 + g * 32 + (r & 3) + ((r >> 2) << 3) + (hi << 2);
                    const float s = (key < qrow) ? sc[g][r] + swv[g][r] : -1e30f;
                    pr[g][r] = s;
                    tmax = fmaxf(tmax, s);
                }
        } else {                     // fully-valid tile
#pragma unroll
            for (int g = 0; g < 2; ++g)
#pragma unroll
                for (int r = 0; r < 16; ++r) {
                    const float s = sc[g][r] + swv[g][r];
                    pr[g][r] = s;
                    tmax = fmaxf(tmax, s);
                }
        }
        tmax = fmaxf(tmax, __shfl_xor(tmax, 32, 64));
        const float mnew = fmaxf(mrow, tmax);
        const float corr = __expf(mrow - mnew);
        float psum = 0.f;
#pragma unroll
        for (int g = 0; g < 2; ++g)
#pragma unroll
            for (int r = 0; r < 16; ++r) {
                const float e = (pr[g][r] > -1e29f) ? __expf(pr[g][r] - mnew) : 0.f;
                pr[g][r] = e;
                psum += e;
            }
        psum += __shfl_xor(psum, 32, 64);
        lrow = lrow * corr + psum;
        mrow = mnew;
#pragma unroll
        for (int r = 0; r < 16; ++r) { accA[r] *= corr; accB[r] *= corr; }

        // ---- P -> bf16 B-fragments (cvt_pk + cross-half exchange) ----
        short8 paf[4];
#pragma unroll
        for (int g = 0; g < 2; ++g) {
            unsigned pk[8];
#pragma unroll
            for (int j = 0; j < 8; ++j) {
                unsigned r_;
                asm("v_cvt_pk_bf16_f32 %0, %1, %2"
                    : "=v"(r_) : "v"(pr[g][2 * j]), "v"(pr[g][2 * j + 1]));
                pk[j] = r_;
            }
            unsigned x0 = (unsigned)__shfl_xor((int)pk[0], 32, 64);
            unsigned x1 = (unsigned)__shfl_xor((int)pk[1], 32, 64);
            unsigned x2 = (unsigned)__shfl_xor((int)pk[2], 32, 64);
            unsigned x3 = (unsigned)__shfl_xor((int)pk[3], 32, 64);
            unsigned x4 = (unsigned)__shfl_xor((int)pk[4], 32, 64);
            unsigned x5 = (unsigned)__shfl_xor((int)pk[5], 32, 64);
            unsigned x6 = (unsigned)__shfl_xor((int)pk[6], 32, 64);
            unsigned x7 = (unsigned)__shfl_xor((int)pk[7], 32, 64);
            union { unsigned u[4]; short8 s; } a0, a1;
            a0.u[0] = hi ? x2 : pk[0];
            a0.u[1] = hi ? x3 : pk[1];
            a0.u[2] = hi ? pk[2] : x0;
            a0.u[3] = hi ? pk[3] : x1;
            a1.u[0] = hi ? x6 : pk[4];
            a1.u[1] = hi ? x7 : pk[5];
            a1.u[2] = hi ? pk[6] : x4;
            a1.u[3] = hi ? pk[7] : x5;
            paf[g * 2 + 0] = a0.s;
            paf[g * 2 + 1] = a1.s;
        }

        // ---- PV (swapped), lane-linear frags ----
        __builtin_amdgcn_s_setprio(1);
#pragma unroll
        for (int cc = 0; cc < 4; ++cc) {
            const short8 va = *reinterpret_cast<const short8*>(
                &Vs[cur][((0 * 4 + cc) * 64 + lane) * 8]);
            const short8 vb = *reinterpret_cast<const short8*>(
                &Vs[cur][((1 * 4 + cc) * 64 + lane) * 8]);
            accA = __builtin_amdgcn_mfma_f32_32x32x16_bf16(va, paf[cc], accA, 0, 0, 0);
            accB = __builtin_amdgcn_mfma_f32_32x32x16_bf16(vb, paf[cc], accB, 0, 0, 0);
        }
        __builtin_amdgcn_s_setprio(0);

        __builtin_amdgcn_sched_barrier(0);
        __builtin_amdgcn_s_barrier();
        __builtin_amdgcn_sched_barrier(0);
    }
#undef ASTAGE

    // ---- epilogue: normalized bf16 partial + (m,l) ----
    const float inv = (lrow > 0.f) ? 1.f / lrow : 0.f;
    ushort* crow_ = ctxP + ((size_t)(bh * 20 + ci) * 128 + (ql * 4 + w)) * 64;
#pragma unroll
    for (int g = 0; g < 4; ++g) {
        ushort4 oA, oB;
        oA.x = (ushort)bf16rne(accA[4 * g + 0] * inv);
        oA.y = (ushort)bf16rne(accA[4 * g + 1] * inv);
        oA.z = (ushort)bf16rne(accA[4 * g + 2] * inv);
        oA.w = (ushort)bf16rne(accA[4 * g + 3] * inv);
        oB.x = (ushort)bf16rne(accB[4 * g + 0] * inv);
        oB.y = (ushort)bf16rne(accB[4 * g + 1] * inv);
        oB.z = (ushort)bf16rne(accB[4 * g + 2] * inv);
        oB.w = (ushort)bf16rne(accB[4 * g + 3] * inv);
        *reinterpret_cast<ushort4*>(&crow_[g * 8 + hi * 4])      = oA;
        *reinterpret_cast<ushort4*>(&crow_[g * 8 + hi * 4 + 32]) = oB;
    }
    if (hi == 0) {
        float2 v; v.x = mrow; v.y = lrow;
        ml[(size_t)(bh * 20 + ci) * 128 + ql * 4 + w] = v;
    }
}

// ---------------------------------------------------------------------------
// Merge chunk partials (1..4 per q-row): out = sum_c w_c * o_c.
// ---------------------------------------------------------------------------
__global__ __launch_bounds__(256) void attn_merge(
    const ushort* __restrict__ ctxP, const float2* __restrict__ ml,
    ushort* __restrict__ ctx)
{
    const size_t idx = ((size_t)blockIdx.x * 256 + threadIdx.x) * 8;
    const int col = (int)(idx & 1023);
    const int row = (int)(idx >> 10);
    const int b = row >> 10, s = row & 1023;
    const int h = col >> 6, dk0 = col & 63;
    const int bh = b * 16 + h;
    const int qb = s >> 7, rl = s & 127;
    const int nch = (qb + 2) >> 1;
    const int cb  = (int)((CBASE_PACK >> (qb * 8)) & 0xff);

    float mm[4], ll[4];
    float m = -1e30f;
#pragma unroll
    for (int c = 0; c < 4; ++c)
        if (c < nch) {
            const float2 v = ml[(size_t)(bh * 20 + cb + c) * 128 + rl];
            mm[c] = v.x; ll[c] = v.y;
            m = fmaxf(m, v.x);
        }
    float wc[4], wsum = 0.f;
#pragma unroll
    for (int c = 0; c < 4; ++c)
        if (c < nch) { wc[c] = ll[c] * __expf(mm[c] - m); wsum += wc[c]; }
    const float inv = (wsum > 0.f) ? 1.f / wsum : 0.f;

    float o[8] = {0.f, 0.f, 0.f, 0.f, 0.f, 0.f, 0.f, 0.f};
#pragma unroll
    for (int c = 0; c < 4; ++c)
        if (c < nch) {
            union { int4 v; ushort u[8]; } p;
            p.v = *reinterpret_cast<const int4*>(
                &ctxP[((size_t)(bh * 20 + cb + c) * 128 + rl) * 64 + dk0]);
            const float wgt = wc[c] * inv;
#pragma unroll
            for (int i = 0; i < 8; ++i)
                o[i] += wgt * __uint_as_float((unsigned)p.u[i] << 16);
        }
    union { int4 v; ushort u[8]; } r;
#pragma unroll
    for (int i = 0; i < 8; ++i) r.u[i] = (ushort)bf16rne(o[i]);
    *reinterpret_cast<int4*>(ctx + idx) = r.v;
}

// ---------------------------------------------------------------------------
// LayerNorm over last dim (1024).
// ---------------------------------------------------------------------------
__global__ __launch_bounds__(256) void layernorm_k(
    const float* __restrict__ x, const float* __restrict__ gamma,
    const float* __restrict__ beta, float* __restrict__ out)
{
    const int row = blockIdx.x;
    const int t   = threadIdx.x;
    const float4 v = *reinterpret_cast<const float4*>(&x[(size_t)row * D_ + (t << 2)]);
    float sum = v.x + v.y + v.z + v.w;
    float sq  = v.x * v.x + v.y * v.y + v.z * v.z + v.w * v.w;
#pragma unroll
    for (int w = 1; w < 64; w <<= 1) {
        sum += __shfl_xor(sum, w, 64);
        sq  += __shfl_xor(sq,  w, 64);
    }
    __shared__ float red[8];
    const int wid = t >> 6;
    if ((t & 63) == 0) { red[wid] = sum; red[wid + 4] = sq; }
    __syncthreads();
    sum = red[0] + red[1] + red[2] + red[3];
    sq  = red[4] + red[5] + red[6] + red[7];
    const float mu  = sum * (1.f / 1024.f);
    const float var = sq * (1.f / 1024.f) - mu * mu;
    const float rs  = rsqrtf(var + 1e-5f);
    const float4 gm = *reinterpret_cast<const float4*>(&gamma[t << 2]);
    const float4 bt = *reinterpret_cast<const float4*>(&beta[t << 2]);
    float4 o;
    o.x = (v.x - mu) * rs * gm.x + bt.x;
    o.y = (v.y - mu) * rs * gm.y + bt.y;
    o.z = (v.z - mu) * rs * gm.z + bt.z;
    o.w = (v.w - mu) * rs * gm.w + bt.w;
    *reinterpret_cast<float4*>(&out[(size_t)row * D_ + (t << 2)]) = o;
}

// ---------------------------------------------------------------------------
extern "C" void kernel_launch(void* const* d_in, const int* in_sizes, int n_in,
                              void* d_out, int out_size, void* d_ws, size_t ws_size,
                              hipStream_t stream)
{
    const float* query  = (const float*)d_in[0];
    const float* key    = (const float*)d_in[1];
    const float* values = (const float*)d_in[2];
    const float* SW     = (const float*)d_in[4];
    const float* Wq     = (const float*)d_in[5];
    const float* bq     = (const float*)d_in[6];
    const float* Wv     = (const float*)d_in[7];
    const float* bv     = (const float*)d_in[8];
    const float* Wo     = (const float*)d_in[9];
    const float* bo     = (const float*)d_in[10];
    const float* gamma  = (const float*)d_in[11];
    const float* beta   = (const float*)d_in[12];

    char* ws = (char*)d_ws;
    const size_t MB = 1024 * 1024;
    ushort* Qh   = (ushort*)(ws);              //  8 MB bf16 [bh][S][DK] (pre-scaled 1/8)
    ushort* Kh   = (ushort*)(ws +  8 * MB);
    ushort* Vt   = (ushort*)(ws + 16 * MB);    //  8 MB bf16 [bh][DK][S]
    ushort* Wqt  = (ushort*)(ws + 24 * MB);    //  2 MB each
    ushort* Wvt  = (ushort*)(ws + 26 * MB);
    ushort* Wot  = (ushort*)(ws + 28 * MB);
    ushort* ctxP = (ushort*)(ws + 30 * MB);    // 21 MB partials (30..51)
    float2* ml   = (float2*)(ws + 52 * MB);    //  1.3 MB
    ushort* ctxm = Qh;                         //  8 MB merged, overlays Qh (dead post-attn)
    float*  xbf  = (float*)(ws + 8 * MB);      // 16 MB fp32, overlays Kh|Vt (dead post-attn)

    const dim3 blk(256);

    transpose_cvt3<<<dim3(32, 32, 3), blk, 0, stream>>>(Wq, Wv, Wo, Wqt, Wvt, Wot);

    // merged Q|K projection straight from fp32 inputs (shared Wq/bq), M = 8192
    gemm_f32a<1><<<dim3(1024), blk, 0, stream>>>(query, key, Wqt, bq, Qh, Kh);
    gemm_f32a<2><<<dim3(512),  blk, 0, stream>>>(values, nullptr, Wvt, bv, Vt, nullptr);

    attn_mfma<<<dim3(1280), blk, 0, stream>>>(Qh, Kh, Vt, SW, ctxP, ml);
    attn_merge<<<dim3(2048), blk, 0, stream>>>(ctxP, ml, ctxm);

    gemm_bf16a<<<dim3(512), blk, 0, stream>>>(ctxm, Wot, bo, query, xbf);

    layernorm_k<<<dim3(4096), blk, 0, stream>>>(xbf, gamma, beta, (float*)d_out);
}

// Round 10
// 127.661 us; speedup vs baseline: 1.8362x; 1.1357x over previous
//
#include <hip/hip_runtime.h>

#define B_ 4
#define S_ 1024
#define D_ 1024
#define H_ 16
#define DK_ 64

typedef __attribute__((ext_vector_type(8))) short short8;
typedef __attribute__((ext_vector_type(4))) float f32x4;
typedef __attribute__((ext_vector_type(16))) float f32x16;

// 16 chunks per bh covering 72 k-tiles: nibble i = chunk i's {qb, t0, nt}
#define QBPACK 0x7777666554433210ULL
#define T0PACK 0xC840A50605040000ULL
#define NTPACK 0x4444455665544642ULL
// per-qb: first chunk index (byte) and chunk count (nibble)
#define CBPACK  0x0C09070503020100ULL
#define NCHPACK 0x43222111U

static __device__ __forceinline__ unsigned bf16rne(float x) {
    unsigned b = __float_as_uint(x);
    return (b + 0x7FFFu + ((b >> 16) & 1u)) >> 16;
}

// ---------------------------------------------------------------------------
// W [1024][1024] fp32 -> Wt [n][k] bf16 (transpose + convert). z selects W.
// ---------------------------------------------------------------------------
__global__ __launch_bounds__(256) void transpose_cvt3(
    const float* __restrict__ W0, const float* __restrict__ W1,
    const float* __restrict__ W2, ushort* __restrict__ T0,
    ushort* __restrict__ T1, ushort* __restrict__ T2)
{
    __shared__ float ts[32][33];
    const float* W = (blockIdx.z == 0) ? W0 : (blockIdx.z == 1) ? W1 : W2;
    ushort*     Wt = (blockIdx.z == 0) ? T0 : (blockIdx.z == 1) ? T1 : T2;
    const int t  = threadIdx.x;
    const int k0 = blockIdx.y * 32, n0 = blockIdx.x * 32;
    const int r  = t >> 3, c4 = (t & 7) * 4;
    const float4 v = *reinterpret_cast<const float4*>(&W[(size_t)(k0 + r) * 1024 + n0 + c4]);
    ts[r][c4] = v.x; ts[r][c4 + 1] = v.y; ts[r][c4 + 2] = v.z; ts[r][c4 + 3] = v.w;
    __syncthreads();
    ushort4 o;
    o.x = (ushort)bf16rne(ts[c4    ][r]);
    o.y = (ushort)bf16rne(ts[c4 + 1][r]);
    o.z = (ushort)bf16rne(ts[c4 + 2][r]);
    o.w = (ushort)bf16rne(ts[c4 + 3][r]);
    *reinterpret_cast<ushort4*>(&Wt[(size_t)(n0 + r) * 1024 + k0 + c4]) = o;
}

// ---------------------------------------------------------------------------
// Merged QKV projection GEMM, fp32-A fused convert. 1536 blocks:
// bm 0..63 -> Q = query@Wq (x1/8, headed), 64..127 -> K = key@Wq (headed),
// 128..191 -> V = values@Wv ([bh][DK][S]). BM=64, BN=128, BK=64, 2-phase dbuf.
// ---------------------------------------------------------------------------
__global__ __launch_bounds__(256) void gemm_qkv(
    const float* __restrict__ q, const float* __restrict__ k,
    const float* __restrict__ v, const ushort* __restrict__ Wqt,
    const ushort* __restrict__ Wvt, const float* __restrict__ bq,
    const float* __restrict__ bv, ushort* __restrict__ Qh,
    ushort* __restrict__ Kh, ushort* __restrict__ Vt)
{
    __shared__ ushort As[2][64 * 64];
    __shared__ ushort Bs[2][128 * 64];

    const int t    = threadIdx.x;
    const int lane = t & 63;
    const int w    = t >> 6;

    const int cpx     = gridDim.x >> 3;
    const int logical = (blockIdx.x & 7) * cpx + (blockIdx.x >> 3);
    const int bm = logical >> 3;
    const int bn = logical & 7;

    const int mode = bm >> 6;                 // 0=Q, 1=K, 2=V
    const float* Xf = (mode == 0) ? q : (mode == 1) ? k : v;
    const ushort* Wt = (mode == 2) ? Wvt : Wqt;
    const float* bias = (mode == 2) ? bv : bq;
    const int rbase = (bm & 63) * 64;

    const int srow   = lane >> 3;
    const int schunk = (lane & 7) ^ srow;
    const float* ap[2];
#pragma unroll
    for (int j = 0; j < 2; ++j)
        ap[j] = Xf + (size_t)(rbase + (j * 4 + w) * 8 + srow) * 1024 + schunk * 8;

    const ushort* bg[4];
#pragma unroll
    for (int j = 0; j < 4; ++j)
        bg[j] = Wt + (size_t)(bn * 128 + (j * 4 + w) * 8 + srow) * 1024 + schunk * 8;

    float4 aRx0, aRy0, aRx1, aRy1;

#define A_ISSUE(k0)                                                              \
    do {                                                                         \
        aRx0 = *reinterpret_cast<const float4*>(ap[0] + (k0));                   \
        aRy0 = *reinterpret_cast<const float4*>(ap[0] + (k0) + 4);               \
        aRx1 = *reinterpret_cast<const float4*>(ap[1] + (k0));                   \
        aRy1 = *reinterpret_cast<const float4*>(ap[1] + (k0) + 4);               \
    } while (0)

#define B_STAGE(buf, k0)                                                         \
    do {                                                                         \
        _Pragma("unroll")                                                        \
        for (int j = 0; j < 4; ++j)                                              \
            __builtin_amdgcn_global_load_lds(                                    \
                (__attribute__((address_space(1))) const void*)(bg[j] + (k0)),   \
                (__attribute__((address_space(3))) void*)&Bs[buf][(j * 4 + w) * 512], \
                16, 0, 0);                                                       \
    } while (0)

#define A_WRITE(buf)                                                             \
    do {                                                                         \
        union { unsigned u[4]; int4 v; } p0, p1;                                 \
        asm("v_cvt_pk_bf16_f32 %0, %1, %2" : "=v"(p0.u[0]) : "v"(aRx0.x), "v"(aRx0.y)); \
        asm("v_cvt_pk_bf16_f32 %0, %1, %2" : "=v"(p0.u[1]) : "v"(aRx0.z), "v"(aRx0.w)); \
        asm("v_cvt_pk_bf16_f32 %0, %1, %2" : "=v"(p0.u[2]) : "v"(aRy0.x), "v"(aRy0.y)); \
        asm("v_cvt_pk_bf16_f32 %0, %1, %2" : "=v"(p0.u[3]) : "v"(aRy0.z), "v"(aRy0.w)); \
        asm("v_cvt_pk_bf16_f32 %0, %1, %2" : "=v"(p1.u[0]) : "v"(aRx1.x), "v"(aRx1.y)); \
        asm("v_cvt_pk_bf16_f32 %0, %1, %2" : "=v"(p1.u[1]) : "v"(aRx1.z), "v"(aRx1.w)); \
        asm("v_cvt_pk_bf16_f32 %0, %1, %2" : "=v"(p1.u[2]) : "v"(aRy1.x), "v"(aRy1.y)); \
        asm("v_cvt_pk_bf16_f32 %0, %1, %2" : "=v"(p1.u[3]) : "v"(aRy1.z), "v"(aRy1.w)); \
        *reinterpret_cast<int4*>(&As[buf][((0 * 4 + w) * 64 + lane) * 8]) = p0.v; \
        *reinterpret_cast<int4*>(&As[buf][((1 * 4 + w) * 64 + lane) * 8]) = p1.v; \
    } while (0)

    const int fr = lane & 15;
    const int fk = lane >> 4;
    const int wm = w >> 1, wn = w & 1;

    f32x4 acc[2][4];
#pragma unroll
    for (int m = 0; m < 2; ++m)
#pragma unroll
        for (int n = 0; n < 4; ++n) acc[m][n] = (f32x4){0.f, 0.f, 0.f, 0.f};

    A_ISSUE(0);
    B_STAGE(0, 0);
    asm volatile("s_waitcnt vmcnt(4)" ::: "memory");
    A_WRITE(0);
    asm volatile("s_waitcnt lgkmcnt(0)" ::: "memory");

#pragma unroll 1
    for (int kt = 0; kt < 16; ++kt) {
        const int cur = kt & 1;
        if (kt + 1 < 16) {
            A_ISSUE((kt + 1) * 64);
            B_STAGE(cur ^ 1, (kt + 1) * 64);
            asm volatile("s_waitcnt vmcnt(8)" ::: "memory");
        } else {
            asm volatile("s_waitcnt vmcnt(0)" ::: "memory");
        }
        __builtin_amdgcn_s_barrier();
        __builtin_amdgcn_sched_barrier(0);
#pragma unroll
        for (int ks = 0; ks < 2; ++ks) {
            short8 af[2], bf[4];
#pragma unroll
            for (int m = 0; m < 2; ++m) {
                const int row = wm * 32 + m * 16 + fr;
                af[m] = *reinterpret_cast<const short8*>(
                    &As[cur][row * 64 + (((ks * 4 + fk) ^ (row & 7)) * 8)]);
            }
#pragma unroll
            for (int n = 0; n < 4; ++n) {
                const int row = wn * 64 + n * 16 + fr;
                bf[n] = *reinterpret_cast<const short8*>(
                    &Bs[cur][row * 64 + (((ks * 4 + fk) ^ (row & 7)) * 8)]);
            }
            __builtin_amdgcn_s_setprio(1);
#pragma unroll
            for (int m = 0; m < 2; ++m)
#pragma unroll
                for (int n = 0; n < 4; ++n)
                    acc[m][n] = __builtin_amdgcn_mfma_f32_16x16x32_bf16(
                        af[m], bf[n], acc[m][n], 0, 0, 0);
            __builtin_amdgcn_s_setprio(0);
        }
        if (kt + 1 < 16) {
            asm volatile("s_waitcnt vmcnt(4)" ::: "memory");
            A_WRITE(cur ^ 1);
            asm volatile("s_waitcnt lgkmcnt(0)" ::: "memory");
        }
        __builtin_amdgcn_sched_barrier(0);
        __builtin_amdgcn_s_barrier();
        __builtin_amdgcn_sched_barrier(0);
    }
#undef A_ISSUE
#undef B_STAGE
#undef A_WRITE

#pragma unroll
    for (int m = 0; m < 2; ++m) {
        const int row0 = rbase + wm * 32 + m * 16 + fk * 4;
#pragma unroll
        for (int n = 0; n < 4; ++n) {
            const int col = bn * 128 + wn * 64 + n * 16 + fr;
            const float bc = bias[col];
            const int b_ = row0 >> 10, s0 = row0 & 1023;
            const int h  = col >> 6,   dk = col & 63;
            if (mode == 0) {
#pragma unroll
                for (int j = 0; j < 4; ++j)
                    Qh[(((size_t)b_ * H_ + h) * S_ + s0 + j) * DK_ + dk] =
                        (ushort)bf16rne((acc[m][n][j] + bc) * 0.125f);
            } else if (mode == 1) {
#pragma unroll
                for (int j = 0; j < 4; ++j)
                    Kh[(((size_t)b_ * H_ + h) * S_ + s0 + j) * DK_ + dk] =
                        (ushort)bf16rne(acc[m][n][j] + bc);
            } else {
                ushort4 pk;
                pk.x = (ushort)bf16rne(acc[m][n][0] + bc);
                pk.y = (ushort)bf16rne(acc[m][n][1] + bc);
                pk.z = (ushort)bf16rne(acc[m][n][2] + bc);
                pk.w = (ushort)bf16rne(acc[m][n][3] + bc);
                *reinterpret_cast<ushort4*>(
                    &Vt[(((size_t)b_ * H_ + h) * DK_ + dk) * S_ + s0]) = pk;
            }
        }
    }
}

// ---------------------------------------------------------------------------
// bf16-A MFMA GEMM (output projection): C = ctx @ Wt^T + bias + resid (fp32).
// ---------------------------------------------------------------------------
__global__ __launch_bounds__(256) void gemm_bf16a(
    const ushort* __restrict__ X, const ushort* __restrict__ Wt,
    const float* __restrict__ bias, const float* __restrict__ resid,
    float* __restrict__ out)
{
    __shared__ ushort As[2][64 * 64];
    __shared__ ushort Bs[2][128 * 64];

    const int t    = threadIdx.x;
    const int lane = t & 63;
    const int w    = t >> 6;

    const int cpx     = gridDim.x >> 3;
    const int logical = (blockIdx.x & 7) * cpx + (blockIdx.x >> 3);
    const int bm = logical >> 3;
    const int bn = logical & 7;

    const int srow   = lane >> 3;
    const int schunk = (lane & 7) ^ srow;
    const ushort* ag[2];
    const ushort* bg[4];
#pragma unroll
    for (int j = 0; j < 2; ++j)
        ag[j] = X  + (size_t)(bm * 64 + (j * 4 + w) * 8 + srow) * 1024 + schunk * 8;
#pragma unroll
    for (int j = 0; j < 4; ++j)
        bg[j] = Wt + (size_t)(bn * 128 + (j * 4 + w) * 8 + srow) * 1024 + schunk * 8;

#define STAGE(buf, k0)                                                           \
    do {                                                                         \
        _Pragma("unroll")                                                        \
        for (int j = 0; j < 2; ++j)                                              \
            __builtin_amdgcn_global_load_lds(                                    \
                (__attribute__((address_space(1))) const void*)(ag[j] + (k0)),   \
                (__attribute__((address_space(3))) void*)&As[buf][(j * 4 + w) * 512], \
                16, 0, 0);                                                       \
        _Pragma("unroll")                                                        \
        for (int j = 0; j < 4; ++j)                                              \
            __builtin_amdgcn_global_load_lds(                                    \
                (__attribute__((address_space(1))) const void*)(bg[j] + (k0)),   \
                (__attribute__((address_space(3))) void*)&Bs[buf][(j * 4 + w) * 512], \
                16, 0, 0);                                                       \
    } while (0)

    const int fr = lane & 15;
    const int fk = lane >> 4;
    const int wm = w >> 1, wn = w & 1;

    f32x4 acc[2][4];
#pragma unroll
    for (int m = 0; m < 2; ++m)
#pragma unroll
        for (int n = 0; n < 4; ++n) acc[m][n] = (f32x4){0.f, 0.f, 0.f, 0.f};

    STAGE(0, 0);
#pragma unroll 1
    for (int kt = 0; kt < 16; ++kt) {
        const int cur = kt & 1;
        if (kt + 1 < 16) {
            STAGE(cur ^ 1, (kt + 1) * 64);
            asm volatile("s_waitcnt vmcnt(6)" ::: "memory");
        } else {
            asm volatile("s_waitcnt vmcnt(0)" ::: "memory");
        }
        __builtin_amdgcn_s_barrier();
        __builtin_amdgcn_sched_barrier(0);
#pragma unroll
        for (int ks = 0; ks < 2; ++ks) {
            short8 af[2], bf[4];
#pragma unroll
            for (int m = 0; m < 2; ++m) {
                const int row = wm * 32 + m * 16 + fr;
                af[m] = *reinterpret_cast<const short8*>(
                    &As[cur][row * 64 + (((ks * 4 + fk) ^ (row & 7)) * 8)]);
            }
#pragma unroll
            for (int n = 0; n < 4; ++n) {
                const int row = wn * 64 + n * 16 + fr;
                bf[n] = *reinterpret_cast<const short8*>(
                    &Bs[cur][row * 64 + (((ks * 4 + fk) ^ (row & 7)) * 8)]);
            }
            __builtin_amdgcn_s_setprio(1);
#pragma unroll
            for (int m = 0; m < 2; ++m)
#pragma unroll
                for (int n = 0; n < 4; ++n)
                    acc[m][n] = __builtin_amdgcn_mfma_f32_16x16x32_bf16(
                        af[m], bf[n], acc[m][n], 0, 0, 0);
            __builtin_amdgcn_s_setprio(0);
        }
        __builtin_amdgcn_sched_barrier(0);
        __builtin_amdgcn_s_barrier();
        __builtin_amdgcn_sched_barrier(0);
    }
#undef STAGE

#pragma unroll
    for (int m = 0; m < 2; ++m) {
        const int row0 = bm * 64 + wm * 32 + m * 16 + fk * 4;
#pragma unroll
        for (int n = 0; n < 4; ++n) {
            const int col = bn * 128 + wn * 64 + n * 16 + fr;
            const float bc = bias[col];
#pragma unroll
            for (int j = 0; j < 4; ++j) {
                const int row = row0 + j;
                out[(size_t)row * 1024 + col] =
                    acc[m][n][j] + bc + resid[(size_t)row * 1024 + col];
            }
        }
    }
}

// ---------------------------------------------------------------------------
// MFMA bf16 flash attention v8: R9 inner structure, grid = EXACTLY 1024
// blocks (64 bh x 16 table-driven chunks, nt in {2..6}) so all blocks are
// co-resident (4/CU) -- no drain tail. b in low bits -> SW L2/L3 reuse.
// ---------------------------------------------------------------------------
__global__ __launch_bounds__(256) void attn_mfma(
    const ushort* __restrict__ Qh, const ushort* __restrict__ Kh,
    const ushort* __restrict__ Vt, const float* __restrict__ SW,
    ushort* __restrict__ ctxP, float2* __restrict__ ml)
{
    __shared__ ushort Ks[2][4096];
    __shared__ ushort Vs[2][4096];

    const int t    = threadIdx.x;
    const int lane = t & 63;
    const int w    = t >> 6;
    // XCD-chunked; 4 consecutive blocks share (h,ci) across b -> SW L2 reuse.
    const int lg = (blockIdx.x & 7) * 128 + (blockIdx.x >> 3);
    const int b  = lg & 3;
    const int hc = lg >> 2;          // 0..255
    const int h  = hc >> 4;
    const int ci = hc & 15;
    const int bh = b * 16 + h;
    const int qb = (int)((QBPACK >> (ci * 4)) & 15);
    const int t0 = (int)((T0PACK >> (ci * 4)) & 15);
    const int nt = (int)((NTPACK >> (ci * 4)) & 15);

    const int ql = lane & 31;
    const int hi = lane >> 5;
    const int qrow = qb * 128 + ql * 4 + w;        // interleaved q-rows

    const ushort* Kg  = Kh + (size_t)bh * S_ * DK_;
    const ushort* Vg  = Vt + (size_t)bh * DK_ * S_;
    const float*  swp = SW + ((size_t)h * S_ + qrow) * S_;

    const ushort* kgp[2];
    const ushort* vgp[2];
#pragma unroll
    for (int j = 0; j < 2; ++j) {
        const int bb = w * 2 + j;
        const int g = bb >> 2, c = bb & 3;
        kgp[j] = Kg + (size_t)(g * 32 + ql) * DK_ + c * 16 + hi * 8;
        vgp[j] = Vg + (size_t)(g * 32 + ql) * S_  + c * 16 + hi * 8;
    }

#define ASTAGE(buf, k0)                                                          \
    do {                                                                         \
        _Pragma("unroll")                                                        \
        for (int j = 0; j < 2; ++j) {                                            \
            const int bb = w * 2 + j;                                            \
            __builtin_amdgcn_global_load_lds(                                    \
                (__attribute__((address_space(1))) const void*)(kgp[j] + (size_t)(k0) * DK_), \
                (__attribute__((address_space(3))) void*)&Ks[buf][bb * 512],     \
                16, 0, 0);                                                       \
            __builtin_amdgcn_global_load_lds(                                    \
                (__attribute__((address_space(1))) const void*)(vgp[j] + (k0)),  \
                (__attribute__((address_space(3))) void*)&Vs[buf][bb * 512],     \
                16, 0, 0);                                                       \
        }                                                                        \
    } while (0)

    // Q B-fragments (pre-scaled by 1/8 in projection)
    short8 qf[4];
    {
        const ushort* Qg = Qh + ((size_t)bh * S_ + qrow) * DK_;
#pragma unroll
        for (int c = 0; c < 4; ++c) {
            union { int4 i; short8 s; } u;
            u.i = *reinterpret_cast<const int4*>(&Qg[c * 16 + hi * 8]);
            qf[c] = u.s;
        }
    }

    f32x16 accA, accB;
#pragma unroll
    for (int r = 0; r < 16; ++r) { accA[r] = 0.f; accB[r] = 0.f; }
    float mrow = -1e30f, lrow = 0.f;

    ASTAGE(0, t0 * 64);

#pragma unroll 1
    for (int kt = 0; kt < nt; ++kt) {
        const int cur = kt & 1;
        const int k0  = (t0 + kt) * 64;
        if (kt + 1 < nt) {
            ASTAGE(cur ^ 1, (t0 + kt + 1) * 64);
            asm volatile("s_waitcnt vmcnt(4)" ::: "memory");
        } else {
            asm volatile("s_waitcnt vmcnt(0)" ::: "memory");
        }
        __builtin_amdgcn_s_barrier();
        __builtin_amdgcn_sched_barrier(0);

        // ---- state_weight gathers first: latency hides under QK MFMAs ----
        float swv[2][16];
#pragma unroll
        for (int g = 0; g < 2; ++g)
#pragma unroll
            for (int j = 0; j < 4; ++j) {
                const float4 v = *reinterpret_cast<const float4*>(
                    &swp[k0 + g * 32 + hi * 4 + j * 8]);
                swv[g][j * 4 + 0] = v.x; swv[g][j * 4 + 1] = v.y;
                swv[g][j * 4 + 2] = v.z; swv[g][j * 4 + 3] = v.w;
            }

        // ---- QK^T (swapped), lane-linear frag reads ----
        f32x16 sc[2];
        __builtin_amdgcn_s_setprio(1);
#pragma unroll
        for (int g = 0; g < 2; ++g) {
#pragma unroll
            for (int r = 0; r < 16; ++r) sc[g][r] = 0.f;
#pragma unroll
            for (int c = 0; c < 4; ++c) {
                const short8 kf = *reinterpret_cast<const short8*>(
                    &Ks[cur][((g * 4 + c) * 64 + lane) * 8]);
                sc[g] = __builtin_amdgcn_mfma_f32_32x32x16_bf16(kf, qf[c], sc[g], 0, 0, 0);
            }
        }
        __builtin_amdgcn_s_setprio(0);

        // ---- scores + online softmax (Q pre-scaled; SW additive) ----
        float pr[2][16];
        float tmax = -1e30f;
        if (t0 + kt >= 2 * qb) {     // masked (diagonal) tile
#pragma unroll
            for (int g = 0; g < 2; ++g)
#pragma unroll
                for (int r = 0; r < 16; ++r) {
                    const int key = k0 + g * 32 + (r & 3) + ((r >> 2) << 3) + (hi << 2);
                    const float s = (key < qrow) ? sc[g][r] + swv[g][r] : -1e30f;
                    pr[g][r] = s;
                    tmax = fmaxf(tmax, s);
                }
        } else {                     // fully-valid tile
#pragma unroll
            for (int g = 0; g < 2; ++g)
#pragma unroll
                for (int r = 0; r < 16; ++r) {
                    const float s = sc[g][r] + swv[g][r];
                    pr[g][r] = s;
                    tmax = fmaxf(tmax, s);
                }
        }
        tmax = fmaxf(tmax, __shfl_xor(tmax, 32, 64));
        const float mnew = fmaxf(mrow, tmax);
        const float corr = __expf(mrow - mnew);
        float psum = 0.f;
#pragma unroll
        for (int g = 0; g < 2; ++g)
#pragma unroll
            for (int r = 0; r < 16; ++r) {
                const float e = (pr[g][r] > -1e29f) ? __expf(pr[g][r] - mnew) : 0.f;
                pr[g][r] = e;
                psum += e;
            }
        psum += __shfl_xor(psum, 32, 64);
        lrow = lrow * corr + psum;
        mrow = mnew;
#pragma unroll
        for (int r = 0; r < 16; ++r) { accA[r] *= corr; accB[r] *= corr; }

        // ---- P -> bf16 B-fragments (cvt_pk + cross-half exchange) ----
        short8 paf[4];
#pragma unroll
        for (int g = 0; g < 2; ++g) {
            unsigned pk[8];
#pragma unroll
            for (int j = 0; j < 8; ++j) {
                unsigned r_;
                asm("v_cvt_pk_bf16_f32 %0, %1, %2"
                    : "=v"(r_) : "v"(pr[g][2 * j]), "v"(pr[g][2 * j + 1]));
                pk[j] = r_;
            }
            unsigned x0 = (unsigned)__shfl_xor((int)pk[0], 32, 64);
            unsigned x1 = (unsigned)__shfl_xor((int)pk[1], 32, 64);
            unsigned x2 = (unsigned)__shfl_xor((int)pk[2], 32, 64);
            unsigned x3 = (unsigned)__shfl_xor((int)pk[3], 32, 64);
            unsigned x4 = (unsigned)__shfl_xor((int)pk[4], 32, 64);
            unsigned x5 = (unsigned)__shfl_xor((int)pk[5], 32, 64);
            unsigned x6 = (unsigned)__shfl_xor((int)pk[6], 32, 64);
            unsigned x7 = (unsigned)__shfl_xor((int)pk[7], 32, 64);
            union { unsigned u[4]; short8 s; } a0, a1;
            a0.u[0] = hi ? x2 : pk[0];
            a0.u[1] = hi ? x3 : pk[1];
            a0.u[2] = hi ? pk[2] : x0;
            a0.u[3] = hi ? pk[3] : x1;
            a1.u[0] = hi ? x6 : pk[4];
            a1.u[1] = hi ? x7 : pk[5];
            a1.u[2] = hi ? pk[6] : x4;
            a1.u[3] = hi ? pk[7] : x5;
            paf[g * 2 + 0] = a0.s;
            paf[g * 2 + 1] = a1.s;
        }

        // ---- PV (swapped), lane-linear frags ----
        __builtin_amdgcn_s_setprio(1);
#pragma unroll
        for (int cc = 0; cc < 4; ++cc) {
            const short8 va = *reinterpret_cast<const short8*>(
                &Vs[cur][((0 * 4 + cc) * 64 + lane) * 8]);
            const short8 vb = *reinterpret_cast<const short8*>(
                &Vs[cur][((1 * 4 + cc) * 64 + lane) * 8]);
            accA = __builtin_amdgcn_mfma_f32_32x32x16_bf16(va, paf[cc], accA, 0, 0, 0);
            accB = __builtin_amdgcn_mfma_f32_32x32x16_bf16(vb, paf[cc], accB, 0, 0, 0);
        }
        __builtin_amdgcn_s_setprio(0);

        __builtin_amdgcn_sched_barrier(0);
        __builtin_amdgcn_s_barrier();
        __builtin_amdgcn_sched_barrier(0);
    }
#undef ASTAGE

    // ---- epilogue: normalized bf16 partial + (m,l) ----
    const float inv = (lrow > 0.f) ? 1.f / lrow : 0.f;
    ushort* crow_ = ctxP + ((size_t)(bh * 16 + ci) * 128 + (ql * 4 + w)) * 64;
#pragma unroll
    for (int g = 0; g < 4; ++g) {
        ushort4 oA, oB;
        oA.x = (ushort)bf16rne(accA[4 * g + 0] * inv);
        oA.y = (ushort)bf16rne(accA[4 * g + 1] * inv);
        oA.z = (ushort)bf16rne(accA[4 * g + 2] * inv);
        oA.w = (ushort)bf16rne(accA[4 * g + 3] * inv);
        oB.x = (ushort)bf16rne(accB[4 * g + 0] * inv);
        oB.y = (ushort)bf16rne(accB[4 * g + 1] * inv);
        oB.z = (ushort)bf16rne(accB[4 * g + 2] * inv);
        oB.w = (ushort)bf16rne(accB[4 * g + 3] * inv);
        *reinterpret_cast<ushort4*>(&crow_[g * 8 + hi * 4])      = oA;
        *reinterpret_cast<ushort4*>(&crow_[g * 8 + hi * 4 + 32]) = oB;
    }
    if (hi == 0) {
        float2 v; v.x = mrow; v.y = lrow;
        ml[(size_t)(bh * 16 + ci) * 128 + ql * 4 + w] = v;
    }
}

// ---------------------------------------------------------------------------
// Merge chunk partials (1..4 per q-row): out = sum_c w_c * o_c.
// ---------------------------------------------------------------------------
__global__ __launch_bounds__(256) void attn_merge(
    const ushort* __restrict__ ctxP, const float2* __restrict__ ml,
    ushort* __restrict__ ctx)
{
    const size_t idx = ((size_t)blockIdx.x * 256 + threadIdx.x) * 8;
    const int col = (int)(idx & 1023);
    const int row = (int)(idx >> 10);
    const int b = row >> 10, s = row & 1023;
    const int h = col >> 6, dk0 = col & 63;
    const int bh = b * 16 + h;
    const int qb = s >> 7, rl = s & 127;
    const int nch = (int)((NCHPACK >> (qb * 4)) & 15);
    const int cb  = (int)((CBPACK >> (qb * 8)) & 255);

    float mm[4], ll[4];
    float m = -1e30f;
#pragma unroll
    for (int c = 0; c < 4; ++c)
        if (c < nch) {
            const float2 v = ml[(size_t)(bh * 16 + cb + c) * 128 + rl];
            mm[c] = v.x; ll[c] = v.y;
            m = fmaxf(m, v.x);
        }
    float wc[4], wsum = 0.f;
#pragma unroll
    for (int c = 0; c < 4; ++c)
        if (c < nch) { wc[c] = ll[c] * __expf(mm[c] - m); wsum += wc[c]; }
    const float inv = (wsum > 0.f) ? 1.f / wsum : 0.f;

    float o[8] = {0.f, 0.f, 0.f, 0.f, 0.f, 0.f, 0.f, 0.f};
#pragma unroll
    for (int c = 0; c < 4; ++c)
        if (c < nch) {
            union { int4 v; ushort u[8]; } p;
            p.v = *reinterpret_cast<const int4*>(
                &ctxP[((size_t)(bh * 16 + cb + c) * 128 + rl) * 64 + dk0]);
            const float wgt = wc[c] * inv;
#pragma unroll
            for (int i = 0; i < 8; ++i)
                o[i] += wgt * __uint_as_float((unsigned)p.u[i] << 16);
        }
    union { int4 v; ushort u[8]; } r;
#pragma unroll
    for (int i = 0; i < 8; ++i) r.u[i] = (ushort)bf16rne(o[i]);
    *reinterpret_cast<int4*>(ctx + idx) = r.v;
}

// ---------------------------------------------------------------------------
// LayerNorm over last dim (1024).
// ---------------------------------------------------------------------------
__global__ __launch_bounds__(256) void layernorm_k(
    const float* __restrict__ x, const float* __restrict__ gamma,
    const float* __restrict__ beta, float* __restrict__ out)
{
    const int row = blockIdx.x;
    const int t   = threadIdx.x;
    const float4 v = *reinterpret_cast<const float4*>(&x[(size_t)row * D_ + (t << 2)]);
    float sum = v.x + v.y + v.z + v.w;
    float sq  = v.x * v.x + v.y * v.y + v.z * v.z + v.w * v.w;
#pragma unroll
    for (int w = 1; w < 64; w <<= 1) {
        sum += __shfl_xor(sum, w, 64);
        sq  += __shfl_xor(sq,  w, 64);
    }
    __shared__ float red[8];
    const int wid = t >> 6;
    if ((t & 63) == 0) { red[wid] = sum; red[wid + 4] = sq; }
    __syncthreads();
    sum = red[0] + red[1] + red[2] + red[3];
    sq  = red[4] + red[5] + red[6] + red[7];
    const float mu  = sum * (1.f / 1024.f);
    const float var = sq * (1.f / 1024.f) - mu * mu;
    const float rs  = rsqrtf(var + 1e-5f);
    const float4 gm = *reinterpret_cast<const float4*>(&gamma[t << 2]);
    const float4 bt = *reinterpret_cast<const float4*>(&beta[t << 2]);
    float4 o;
    o.x = (v.x - mu) * rs * gm.x + bt.x;
    o.y = (v.y - mu) * rs * gm.y + bt.y;
    o.z = (v.z - mu) * rs * gm.z + bt.z;
    o.w = (v.w - mu) * rs * gm.w + bt.w;
    *reinterpret_cast<float4*>(&out[(size_t)row * D_ + (t << 2)]) = o;
}

// ---------------------------------------------------------------------------
extern "C" void kernel_launch(void* const* d_in, const int* in_sizes, int n_in,
                              void* d_out, int out_size, void* d_ws, size_t ws_size,
                              hipStream_t stream)
{
    const float* query  = (const float*)d_in[0];
    const float* key    = (const float*)d_in[1];
    const float* values = (const float*)d_in[2];
    const float* SW     = (const float*)d_in[4];
    const float* Wq     = (const float*)d_in[5];
    const float* bq     = (const float*)d_in[6];
    const float* Wv     = (const float*)d_in[7];
    const float* bv     = (const float*)d_in[8];
    const float* Wo     = (const float*)d_in[9];
    const float* bo     = (const float*)d_in[10];
    const float* gamma  = (const float*)d_in[11];
    const float* beta   = (const float*)d_in[12];

    char* ws = (char*)d_ws;
    const size_t MB = 1024 * 1024;
    ushort* Qh   = (ushort*)(ws);              //  8 MB bf16 [bh][S][DK] (pre-scaled 1/8)
    ushort* Kh   = (ushort*)(ws +  8 * MB);
    ushort* Vt   = (ushort*)(ws + 16 * MB);    //  8 MB bf16 [bh][DK][S]
    ushort* Wqt  = (ushort*)(ws + 24 * MB);    //  2 MB each
    ushort* Wvt  = (ushort*)(ws + 26 * MB);
    ushort* Wot  = (ushort*)(ws + 28 * MB);
    ushort* ctxP = (ushort*)(ws + 30 * MB);    // 16 MB partials (30..46)
    float2* ml   = (float2*)(ws + 46 * MB);    //  1 MB
    ushort* ctxm = Qh;                         //  8 MB merged, overlays Qh (dead post-attn)
    float*  xbf  = (float*)(ws + 8 * MB);      // 16 MB fp32, overlays Kh|Vt (dead post-attn)

    const dim3 blk(256);

    transpose_cvt3<<<dim3(32, 32, 3), blk, 0, stream>>>(Wq, Wv, Wo, Wqt, Wvt, Wot);

    gemm_qkv<<<dim3(1536), blk, 0, stream>>>(query, key, values, Wqt, Wvt,
                                             bq, bv, Qh, Kh, Vt);

    attn_mfma<<<dim3(1024), blk, 0, stream>>>(Qh, Kh, Vt, SW, ctxP, ml);
    attn_merge<<<dim3(2048), blk, 0, stream>>>(ctxP, ml, ctxm);

    gemm_bf16a<<<dim3(512), blk, 0, stream>>>(ctxm, Wot, bo, query, xbf);

    layernorm_k<<<dim3(4096), blk, 0, stream>>>(xbf, gamma, beta, (float*)d_out);
}

// Round 11
// 126.266 us; speedup vs baseline: 1.8565x; 1.0110x over previous
//
#include <hip/hip_runtime.h>

#define B_ 4
#define S_ 1024
#define D_ 1024
#define H_ 16
#define DK_ 64

typedef __attribute__((ext_vector_type(8))) short short8;
typedef __attribute__((ext_vector_type(4))) float f32x4;
typedef __attribute__((ext_vector_type(16))) float f32x16;

// 16 chunks per bh covering 72 k-tiles: nibble i = chunk i's {qb, t0, nt}
#define QBPACK 0x7777666554433210ULL
#define T0PACK 0xC840A50605040000ULL
#define NTPACK 0x4444455665544642ULL
// per-qb: first chunk index (byte) and chunk count (nibble)
#define CBPACK  0x0C09070503020100ULL
#define NCHPACK 0x43222111U

static __device__ __forceinline__ unsigned bf16rne(float x) {
    unsigned b = __float_as_uint(x);
    return (b + 0x7FFFu + ((b >> 16) & 1u)) >> 16;
}

// ---------------------------------------------------------------------------
// W [1024][1024] fp32 -> Wt [n][k] bf16 (transpose + convert). z selects W.
// ---------------------------------------------------------------------------
__global__ __launch_bounds__(256) void transpose_cvt3(
    const float* __restrict__ W0, const float* __restrict__ W1,
    const float* __restrict__ W2, ushort* __restrict__ T0,
    ushort* __restrict__ T1, ushort* __restrict__ T2)
{
    __shared__ float ts[32][33];
    const float* W = (blockIdx.z == 0) ? W0 : (blockIdx.z == 1) ? W1 : W2;
    ushort*     Wt = (blockIdx.z == 0) ? T0 : (blockIdx.z == 1) ? T1 : T2;
    const int t  = threadIdx.x;
    const int k0 = blockIdx.y * 32, n0 = blockIdx.x * 32;
    const int r  = t >> 3, c4 = (t & 7) * 4;
    const float4 v = *reinterpret_cast<const float4*>(&W[(size_t)(k0 + r) * 1024 + n0 + c4]);
    ts[r][c4] = v.x; ts[r][c4 + 1] = v.y; ts[r][c4 + 2] = v.z; ts[r][c4 + 3] = v.w;
    __syncthreads();
    ushort4 o;
    o.x = (ushort)bf16rne(ts[c4    ][r]);
    o.y = (ushort)bf16rne(ts[c4 + 1][r]);
    o.z = (ushort)bf16rne(ts[c4 + 2][r]);
    o.w = (ushort)bf16rne(ts[c4 + 3][r]);
    *reinterpret_cast<ushort4*>(&Wt[(size_t)(n0 + r) * 1024 + k0 + c4]) = o;
}

// ---------------------------------------------------------------------------
// Merged QKV projection GEMM, fp32-A fused convert, 2-tile-deep A prefetch.
// bm 0..63 -> Q = query@Wq (x1/8, headed), 64..127 -> K = key@Wq (headed),
// 128..191 -> V = values@Wv ([bh][DK][S]). BM=64, BN=128, BK=64, 2-phase dbuf.
// A register sets S0/S1 alternate (named, literal-indexed); A(kt+2) issued at
// iteration top -> ~2 tiles of latency cover; vmcnt(4) drains A(kt+1)+B(kt).
// ---------------------------------------------------------------------------
__global__ __launch_bounds__(256) void gemm_qkv(
    const float* __restrict__ q, const float* __restrict__ k,
    const float* __restrict__ v, const ushort* __restrict__ Wqt,
    const ushort* __restrict__ Wvt, const float* __restrict__ bq,
    const float* __restrict__ bv, ushort* __restrict__ Qh,
    ushort* __restrict__ Kh, ushort* __restrict__ Vt)
{
    __shared__ ushort As[2][64 * 64];
    __shared__ ushort Bs[2][128 * 64];

    const int t    = threadIdx.x;
    const int lane = t & 63;
    const int w    = t >> 6;

    const int cpx     = gridDim.x >> 3;
    const int logical = (blockIdx.x & 7) * cpx + (blockIdx.x >> 3);
    const int bm = logical >> 3;
    const int bn = logical & 7;

    const int mode = bm >> 6;                 // 0=Q, 1=K, 2=V
    const float* Xf = (mode == 0) ? q : (mode == 1) ? k : v;
    const ushort* Wt = (mode == 2) ? Wvt : Wqt;
    const float* bias = (mode == 2) ? bv : bq;
    const int rbase = (bm & 63) * 64;

    const int srow   = lane >> 3;
    const int schunk = (lane & 7) ^ srow;
    const float* ap[2];
#pragma unroll
    for (int j = 0; j < 2; ++j)
        ap[j] = Xf + (size_t)(rbase + (j * 4 + w) * 8 + srow) * 1024 + schunk * 8;

    const ushort* bg[4];
#pragma unroll
    for (int j = 0; j < 4; ++j)
        bg[j] = Wt + (size_t)(bn * 128 + (j * 4 + w) * 8 + srow) * 1024 + schunk * 8;

    // two named A register sets (literal indices only)
    float4 s0x0, s0y0, s0x1, s0y1;
    float4 s1x0, s1y0, s1x1, s1y1;

#define A_ISSUE0(k0)                                                             \
    do {                                                                         \
        s0x0 = *reinterpret_cast<const float4*>(ap[0] + (k0));                   \
        s0y0 = *reinterpret_cast<const float4*>(ap[0] + (k0) + 4);               \
        s0x1 = *reinterpret_cast<const float4*>(ap[1] + (k0));                   \
        s0y1 = *reinterpret_cast<const float4*>(ap[1] + (k0) + 4);               \
    } while (0)

#define A_ISSUE1(k0)                                                             \
    do {                                                                         \
        s1x0 = *reinterpret_cast<const float4*>(ap[0] + (k0));                   \
        s1y0 = *reinterpret_cast<const float4*>(ap[0] + (k0) + 4);               \
        s1x1 = *reinterpret_cast<const float4*>(ap[1] + (k0));                   \
        s1y1 = *reinterpret_cast<const float4*>(ap[1] + (k0) + 4);               \
    } while (0)

#define B_STAGE(buf, k0)                                                         \
    do {                                                                         \
        _Pragma("unroll")                                                        \
        for (int j = 0; j < 4; ++j)                                              \
            __builtin_amdgcn_global_load_lds(                                    \
                (__attribute__((address_space(1))) const void*)(bg[j] + (k0)),   \
                (__attribute__((address_space(3))) void*)&Bs[buf][(j * 4 + w) * 512], \
                16, 0, 0);                                                       \
    } while (0)

#define A_WRITE_SET(buf, X0, Y0, X1, Y1)                                         \
    do {                                                                         \
        union { unsigned u[4]; int4 v; } p0, p1;                                 \
        asm("v_cvt_pk_bf16_f32 %0, %1, %2" : "=v"(p0.u[0]) : "v"(X0.x), "v"(X0.y)); \
        asm("v_cvt_pk_bf16_f32 %0, %1, %2" : "=v"(p0.u[1]) : "v"(X0.z), "v"(X0.w)); \
        asm("v_cvt_pk_bf16_f32 %0, %1, %2" : "=v"(p0.u[2]) : "v"(Y0.x), "v"(Y0.y)); \
        asm("v_cvt_pk_bf16_f32 %0, %1, %2" : "=v"(p0.u[3]) : "v"(Y0.z), "v"(Y0.w)); \
        asm("v_cvt_pk_bf16_f32 %0, %1, %2" : "=v"(p1.u[0]) : "v"(X1.x), "v"(X1.y)); \
        asm("v_cvt_pk_bf16_f32 %0, %1, %2" : "=v"(p1.u[1]) : "v"(X1.z), "v"(X1.w)); \
        asm("v_cvt_pk_bf16_f32 %0, %1, %2" : "=v"(p1.u[2]) : "v"(Y1.x), "v"(Y1.y)); \
        asm("v_cvt_pk_bf16_f32 %0, %1, %2" : "=v"(p1.u[3]) : "v"(Y1.z), "v"(Y1.w)); \
        *reinterpret_cast<int4*>(&As[buf][((0 * 4 + w) * 64 + lane) * 8]) = p0.v; \
        *reinterpret_cast<int4*>(&As[buf][((1 * 4 + w) * 64 + lane) * 8]) = p1.v; \
    } while (0)

    const int fr = lane & 15;
    const int fk = lane >> 4;
    const int wm = w >> 1, wn = w & 1;

    f32x4 acc[2][4];
#pragma unroll
    for (int m = 0; m < 2; ++m)
#pragma unroll
        for (int n = 0; n < 4; ++n) acc[m][n] = (f32x4){0.f, 0.f, 0.f, 0.f};

#define MFMA_TILE(buf)                                                           \
    do {                                                                         \
        _Pragma("unroll")                                                        \
        for (int ks = 0; ks < 2; ++ks) {                                         \
            short8 af[2], bf[4];                                                 \
            _Pragma("unroll")                                                    \
            for (int m = 0; m < 2; ++m) {                                        \
                const int row = wm * 32 + m * 16 + fr;                           \
                af[m] = *reinterpret_cast<const short8*>(                        \
                    &As[buf][row * 64 + (((ks * 4 + fk) ^ (row & 7)) * 8)]);     \
            }                                                                    \
            _Pragma("unroll")                                                    \
            for (int n = 0; n < 4; ++n) {                                        \
                const int row = wn * 64 + n * 16 + fr;                           \
                bf[n] = *reinterpret_cast<const short8*>(                        \
                    &Bs[buf][row * 64 + (((ks * 4 + fk) ^ (row & 7)) * 8)]);     \
            }                                                                    \
            __builtin_amdgcn_s_setprio(1);                                       \
            _Pragma("unroll")                                                    \
            for (int m = 0; m < 2; ++m)                                          \
                _Pragma("unroll")                                                \
                for (int n = 0; n < 4; ++n)                                      \
                    acc[m][n] = __builtin_amdgcn_mfma_f32_16x16x32_bf16(         \
                        af[m], bf[n], acc[m][n], 0, 0, 0);                       \
            __builtin_amdgcn_s_setprio(0);                                       \
        }                                                                        \
    } while (0)

    // ---- prologue: A(0)->S0, A(1)->S1, B(0); write A(0) ----
    A_ISSUE0(0);
    A_ISSUE1(64);
    B_STAGE(0, 0);
    asm volatile("s_waitcnt vmcnt(8)" ::: "memory");   // A(0) landed
    A_WRITE_SET(0, s0x0, s0y0, s0x1, s0y1);
    asm volatile("s_waitcnt lgkmcnt(0)" ::: "memory");
    __builtin_amdgcn_sched_barrier(0);

#pragma unroll 1
    for (int kt = 0; kt < 14; kt += 2) {
        // ---- tile kt (buf 0): S1 holds A(kt+1); issue A(kt+2)->S0 ----
        A_ISSUE0((kt + 2) * 64);
        asm volatile("s_waitcnt vmcnt(4)" ::: "memory");  // A(kt+1)+B(kt) landed
        __builtin_amdgcn_s_barrier();
        __builtin_amdgcn_sched_barrier(0);
        B_STAGE(1, (kt + 1) * 64);
        MFMA_TILE(0);
        A_WRITE_SET(1, s1x0, s1y0, s1x1, s1y1);           // A(kt+1) -> As[1]
        asm volatile("s_waitcnt lgkmcnt(0)" ::: "memory");
        __builtin_amdgcn_sched_barrier(0);
        __builtin_amdgcn_s_barrier();
        __builtin_amdgcn_sched_barrier(0);

        // ---- tile kt+1 (buf 1): S0 holds A(kt+2); issue A(kt+3)->S1 ----
        A_ISSUE1((kt + 3) * 64);
        asm volatile("s_waitcnt vmcnt(4)" ::: "memory");  // A(kt+2)+B(kt+1) landed
        __builtin_amdgcn_s_barrier();
        __builtin_amdgcn_sched_barrier(0);
        B_STAGE(0, (kt + 2) * 64);
        MFMA_TILE(1);
        A_WRITE_SET(0, s0x0, s0y0, s0x1, s0y1);           // A(kt+2) -> As[0]
        asm volatile("s_waitcnt lgkmcnt(0)" ::: "memory");
        __builtin_amdgcn_sched_barrier(0);
        __builtin_amdgcn_s_barrier();
        __builtin_amdgcn_sched_barrier(0);
    }

    // ---- epilogue: tiles 14 (buf 0) and 15 (buf 1) ----
    asm volatile("s_waitcnt vmcnt(0)" ::: "memory");      // A(15)+B(14) landed
    __builtin_amdgcn_s_barrier();
    __builtin_amdgcn_sched_barrier(0);
    B_STAGE(1, 15 * 64);
    MFMA_TILE(0);
    A_WRITE_SET(1, s1x0, s1y0, s1x1, s1y1);               // A(15) -> As[1]
    asm volatile("s_waitcnt lgkmcnt(0)" ::: "memory");
    __builtin_amdgcn_sched_barrier(0);
    __builtin_amdgcn_s_barrier();
    __builtin_amdgcn_sched_barrier(0);

    asm volatile("s_waitcnt vmcnt(0)" ::: "memory");      // B(15) landed
    __builtin_amdgcn_s_barrier();
    __builtin_amdgcn_sched_barrier(0);
    MFMA_TILE(1);

#undef A_ISSUE0
#undef A_ISSUE1
#undef B_STAGE
#undef A_WRITE_SET
#undef MFMA_TILE

#pragma unroll
    for (int m = 0; m < 2; ++m) {
        const int row0 = rbase + wm * 32 + m * 16 + fk * 4;
#pragma unroll
        for (int n = 0; n < 4; ++n) {
            const int col = bn * 128 + wn * 64 + n * 16 + fr;
            const float bc = bias[col];
            const int b_ = row0 >> 10, s0 = row0 & 1023;
            const int h  = col >> 6,   dk = col & 63;
            if (mode == 0) {
#pragma unroll
                for (int j = 0; j < 4; ++j)
                    Qh[(((size_t)b_ * H_ + h) * S_ + s0 + j) * DK_ + dk] =
                        (ushort)bf16rne((acc[m][n][j] + bc) * 0.125f);
            } else if (mode == 1) {
#pragma unroll
                for (int j = 0; j < 4; ++j)
                    Kh[(((size_t)b_ * H_ + h) * S_ + s0 + j) * DK_ + dk] =
                        (ushort)bf16rne(acc[m][n][j] + bc);
            } else {
                ushort4 pk;
                pk.x = (ushort)bf16rne(acc[m][n][0] + bc);
                pk.y = (ushort)bf16rne(acc[m][n][1] + bc);
                pk.z = (ushort)bf16rne(acc[m][n][2] + bc);
                pk.w = (ushort)bf16rne(acc[m][n][3] + bc);
                *reinterpret_cast<ushort4*>(
                    &Vt[(((size_t)b_ * H_ + h) * DK_ + dk) * S_ + s0]) = pk;
            }
        }
    }
}

// ---------------------------------------------------------------------------
// bf16-A MFMA GEMM (output projection): C = ctx @ Wt^T + bias + resid (fp32).
// ---------------------------------------------------------------------------
__global__ __launch_bounds__(256) void gemm_bf16a(
    const ushort* __restrict__ X, const ushort* __restrict__ Wt,
    const float* __restrict__ bias, const float* __restrict__ resid,
    float* __restrict__ out)
{
    __shared__ ushort As[2][64 * 64];
    __shared__ ushort Bs[2][128 * 64];

    const int t    = threadIdx.x;
    const int lane = t & 63;
    const int w    = t >> 6;

    const int cpx     = gridDim.x >> 3;
    const int logical = (blockIdx.x & 7) * cpx + (blockIdx.x >> 3);
    const int bm = logical >> 3;
    const int bn = logical & 7;

    const int srow   = lane >> 3;
    const int schunk = (lane & 7) ^ srow;
    const ushort* ag[2];
    const ushort* bg[4];
#pragma unroll
    for (int j = 0; j < 2; ++j)
        ag[j] = X  + (size_t)(bm * 64 + (j * 4 + w) * 8 + srow) * 1024 + schunk * 8;
#pragma unroll
    for (int j = 0; j < 4; ++j)
        bg[j] = Wt + (size_t)(bn * 128 + (j * 4 + w) * 8 + srow) * 1024 + schunk * 8;

#define STAGE(buf, k0)                                                           \
    do {                                                                         \
        _Pragma("unroll")                                                        \
        for (int j = 0; j < 2; ++j)                                              \
            __builtin_amdgcn_global_load_lds(                                    \
                (__attribute__((address_space(1))) const void*)(ag[j] + (k0)),   \
                (__attribute__((address_space(3))) void*)&As[buf][(j * 4 + w) * 512], \
                16, 0, 0);                                                       \
        _Pragma("unroll")                                                        \
        for (int j = 0; j < 4; ++j)                                              \
            __builtin_amdgcn_global_load_lds(                                    \
                (__attribute__((address_space(1))) const void*)(bg[j] + (k0)),   \
                (__attribute__((address_space(3))) void*)&Bs[buf][(j * 4 + w) * 512], \
                16, 0, 0);                                                       \
    } while (0)

    const int fr = lane & 15;
    const int fk = lane >> 4;
    const int wm = w >> 1, wn = w & 1;

    f32x4 acc[2][4];
#pragma unroll
    for (int m = 0; m < 2; ++m)
#pragma unroll
        for (int n = 0; n < 4; ++n) acc[m][n] = (f32x4){0.f, 0.f, 0.f, 0.f};

    STAGE(0, 0);
#pragma unroll 1
    for (int kt = 0; kt < 16; ++kt) {
        const int cur = kt & 1;
        if (kt + 1 < 16) {
            STAGE(cur ^ 1, (kt + 1) * 64);
            asm volatile("s_waitcnt vmcnt(6)" ::: "memory");
        } else {
            asm volatile("s_waitcnt vmcnt(0)" ::: "memory");
        }
        __builtin_amdgcn_s_barrier();
        __builtin_amdgcn_sched_barrier(0);
#pragma unroll
        for (int ks = 0; ks < 2; ++ks) {
            short8 af[2], bf[4];
#pragma unroll
            for (int m = 0; m < 2; ++m) {
                const int row = wm * 32 + m * 16 + fr;
                af[m] = *reinterpret_cast<const short8*>(
                    &As[cur][row * 64 + (((ks * 4 + fk) ^ (row & 7)) * 8)]);
            }
#pragma unroll
            for (int n = 0; n < 4; ++n) {
                const int row = wn * 64 + n * 16 + fr;
                bf[n] = *reinterpret_cast<const short8*>(
                    &Bs[cur][row * 64 + (((ks * 4 + fk) ^ (row & 7)) * 8)]);
            }
            __builtin_amdgcn_s_setprio(1);
#pragma unroll
            for (int m = 0; m < 2; ++m)
#pragma unroll
                for (int n = 0; n < 4; ++n)
                    acc[m][n] = __builtin_amdgcn_mfma_f32_16x16x32_bf16(
                        af[m], bf[n], acc[m][n], 0, 0, 0);
            __builtin_amdgcn_s_setprio(0);
        }
        __builtin_amdgcn_sched_barrier(0);
        __builtin_amdgcn_s_barrier();
        __builtin_amdgcn_sched_barrier(0);
    }
#undef STAGE

#pragma unroll
    for (int m = 0; m < 2; ++m) {
        const int row0 = bm * 64 + wm * 32 + m * 16 + fk * 4;
#pragma unroll
        for (int n = 0; n < 4; ++n) {
            const int col = bn * 128 + wn * 64 + n * 16 + fr;
            const float bc = bias[col];
#pragma unroll
            for (int j = 0; j < 4; ++j) {
                const int row = row0 + j;
                out[(size_t)row * 1024 + col] =
                    acc[m][n][j] + bc + resid[(size_t)row * 1024 + col];
            }
        }
    }
}

// ---------------------------------------------------------------------------
// MFMA bf16 flash attention v8 (unchanged from R10): 1024 blocks (64 bh x 16
// table-driven chunks), fragment-major LDS, counted vmcnt dbuf, SW-first.
// ---------------------------------------------------------------------------
__global__ __launch_bounds__(256) void attn_mfma(
    const ushort* __restrict__ Qh, const ushort* __restrict__ Kh,
    const ushort* __restrict__ Vt, const float* __restrict__ SW,
    ushort* __restrict__ ctxP, float2* __restrict__ ml)
{
    __shared__ ushort Ks[2][4096];
    __shared__ ushort Vs[2][4096];

    const int t    = threadIdx.x;
    const int lane = t & 63;
    const int w    = t >> 6;
    const int lg = (blockIdx.x & 7) * 128 + (blockIdx.x >> 3);
    const int b  = lg & 3;
    const int hc = lg >> 2;
    const int h  = hc >> 4;
    const int ci = hc & 15;
    const int bh = b * 16 + h;
    const int qb = (int)((QBPACK >> (ci * 4)) & 15);
    const int t0 = (int)((T0PACK >> (ci * 4)) & 15);
    const int nt = (int)((NTPACK >> (ci * 4)) & 15);

    const int ql = lane & 31;
    const int hi = lane >> 5;
    const int qrow = qb * 128 + ql * 4 + w;

    const ushort* Kg  = Kh + (size_t)bh * S_ * DK_;
    const ushort* Vg  = Vt + (size_t)bh * DK_ * S_;
    const float*  swp = SW + ((size_t)h * S_ + qrow) * S_;

    const ushort* kgp[2];
    const ushort* vgp[2];
#pragma unroll
    for (int j = 0; j < 2; ++j) {
        const int bb = w * 2 + j;
        const int g = bb >> 2, c = bb & 3;
        kgp[j] = Kg + (size_t)(g * 32 + ql) * DK_ + c * 16 + hi * 8;
        vgp[j] = Vg + (size_t)(g * 32 + ql) * S_  + c * 16 + hi * 8;
    }

#define ASTAGE(buf, k0)                                                          \
    do {                                                                         \
        _Pragma("unroll")                                                        \
        for (int j = 0; j < 2; ++j) {                                            \
            const int bb = w * 2 + j;                                            \
            __builtin_amdgcn_global_load_lds(                                    \
                (__attribute__((address_space(1))) const void*)(kgp[j] + (size_t)(k0) * DK_), \
                (__attribute__((address_space(3))) void*)&Ks[buf][bb * 512],     \
                16, 0, 0);                                                       \
            __builtin_amdgcn_global_load_lds(                                    \
                (__attribute__((address_space(1))) const void*)(vgp[j] + (k0)),  \
                (__attribute__((address_space(3))) void*)&Vs[buf][bb * 512],     \
                16, 0, 0);                                                       \
        }                                                                        \
    } while (0)

    short8 qf[4];
    {
        const ushort* Qg = Qh + ((size_t)bh * S_ + qrow) * DK_;
#pragma unroll
        for (int c = 0; c < 4; ++c) {
            union { int4 i; short8 s; } u;
            u.i = *reinterpret_cast<const int4*>(&Qg[c * 16 + hi * 8]);
            qf[c] = u.s;
        }
    }

    f32x16 accA, accB;
#pragma unroll
    for (int r = 0; r < 16; ++r) { accA[r] = 0.f; accB[r] = 0.f; }
    float mrow = -1e30f, lrow = 0.f;

    ASTAGE(0, t0 * 64);

#pragma unroll 1
    for (int kt = 0; kt < nt; ++kt) {
        const int cur = kt & 1;
        const int k0  = (t0 + kt) * 64;
        if (kt + 1 < nt) {
            ASTAGE(cur ^ 1, (t0 + kt + 1) * 64);
            asm volatile("s_waitcnt vmcnt(4)" ::: "memory");
        } else {
            asm volatile("s_waitcnt vmcnt(0)" ::: "memory");
        }
        __builtin_amdgcn_s_barrier();
        __builtin_amdgcn_sched_barrier(0);

        float swv[2][16];
#pragma unroll
        for (int g = 0; g < 2; ++g)
#pragma unroll
            for (int j = 0; j < 4; ++j) {
                const float4 v = *reinterpret_cast<const float4*>(
                    &swp[k0 + g * 32 + hi * 4 + j * 8]);
                swv[g][j * 4 + 0] = v.x; swv[g][j * 4 + 1] = v.y;
                swv[g][j * 4 + 2] = v.z; swv[g][j * 4 + 3] = v.w;
            }

        f32x16 sc[2];
        __builtin_amdgcn_s_setprio(1);
#pragma unroll
        for (int g = 0; g < 2; ++g) {
#pragma unroll
            for (int r = 0; r < 16; ++r) sc[g][r] = 0.f;
#pragma unroll
            for (int c = 0; c < 4; ++c) {
                const short8 kf = *reinterpret_cast<const short8*>(
                    &Ks[cur][((g * 4 + c) * 64 + lane) * 8]);
                sc[g] = __builtin_amdgcn_mfma_f32_32x32x16_bf16(kf, qf[c], sc[g], 0, 0, 0);
            }
        }
        __builtin_amdgcn_s_setprio(0);

        float pr[2][16];
        float tmax = -1e30f;
        if (t0 + kt >= 2 * qb) {
#pragma unroll
            for (int g = 0; g < 2; ++g)
#pragma unroll
                for (int r = 0; r < 16; ++r) {
                    const int key = k0 + g * 32 + (r & 3) + ((r >> 2) << 3) + (hi << 2);
                    const float s = (key < qrow) ? sc[g][r] + swv[g][r] : -1e30f;
                    pr[g][r] = s;
                    tmax = fmaxf(tmax, s);
                }
        } else {
#pragma unroll
            for (int g = 0; g < 2; ++g)
#pragma unroll
                for (int r = 0; r < 16; ++r) {
                    const float s = sc[g][r] + swv[g][r];
                    pr[g][r] = s;
                    tmax = fmaxf(tmax, s);
                }
        }
        tmax = fmaxf(tmax, __shfl_xor(tmax, 32, 64));
        const float mnew = fmaxf(mrow, tmax);
        const float corr = __expf(mrow - mnew);
        float psum = 0.f;
#pragma unroll
        for (int g = 0; g < 2; ++g)
#pragma unroll
            for (int r = 0; r < 16; ++r) {
                const float e = (pr[g][r] > -1e29f) ? __expf(pr[g][r] - mnew) : 0.f;
                pr[g][r] = e;
                psum += e;
            }
        psum += __shfl_xor(psum, 32, 64);
        lrow = lrow * corr + psum;
        mrow = mnew;
#pragma unroll
        for (int r = 0; r < 16; ++r) { accA[r] *= corr; accB[r] *= corr; }

        short8 paf[4];
#pragma unroll
        for (int g = 0; g < 2; ++g) {
            unsigned pk[8];
#pragma unroll
            for (int j = 0; j < 8; ++j) {
                unsigned r_;
                asm("v_cvt_pk_bf16_f32 %0, %1, %2"
                    : "=v"(r_) : "v"(pr[g][2 * j]), "v"(pr[g][2 * j + 1]));
                pk[j] = r_;
            }
            unsigned x0 = (unsigned)__shfl_xor((int)pk[0], 32, 64);
            unsigned x1 = (unsigned)__shfl_xor((int)pk[1], 32, 64);
            unsigned x2 = (unsigned)__shfl_xor((int)pk[2], 32, 64);
            unsigned x3 = (unsigned)__shfl_xor((int)pk[3], 32, 64);
            unsigned x4 = (unsigned)__shfl_xor((int)pk[4], 32, 64);
            unsigned x5 = (unsigned)__shfl_xor((int)pk[5], 32, 64);
            unsigned x6 = (unsigned)__shfl_xor((int)pk[6], 32, 64);
            unsigned x7 = (unsigned)__shfl_xor((int)pk[7], 32, 64);
            union { unsigned u[4]; short8 s; } a0, a1;
            a0.u[0] = hi ? x2 : pk[0];
            a0.u[1] = hi ? x3 : pk[1];
            a0.u[2] = hi ? pk[2] : x0;
            a0.u[3] = hi ? pk[3] : x1;
            a1.u[0] = hi ? x6 : pk[4];
            a1.u[1] = hi ? x7 : pk[5];
            a1.u[2] = hi ? pk[6] : x4;
            a1.u[3] = hi ? pk[7] : x5;
            paf[g * 2 + 0] = a0.s;
            paf[g * 2 + 1] = a1.s;
        }

        __builtin_amdgcn_s_setprio(1);
#pragma unroll
        for (int cc = 0; cc < 4; ++cc) {
            const short8 va = *reinterpret_cast<const short8*>(
                &Vs[cur][((0 * 4 + cc) * 64 + lane) * 8]);
            const short8 vb = *reinterpret_cast<const short8*>(
                &Vs[cur][((1 * 4 + cc) * 64 + lane) * 8]);
            accA = __builtin_amdgcn_mfma_f32_32x32x16_bf16(va, paf[cc], accA, 0, 0, 0);
            accB = __builtin_amdgcn_mfma_f32_32x32x16_bf16(vb, paf[cc], accB, 0, 0, 0);
        }
        __builtin_amdgcn_s_setprio(0);

        __builtin_amdgcn_sched_barrier(0);
        __builtin_amdgcn_s_barrier();
        __builtin_amdgcn_sched_barrier(0);
    }
#undef ASTAGE

    const float inv = (lrow > 0.f) ? 1.f / lrow : 0.f;
    ushort* crow_ = ctxP + ((size_t)(bh * 16 + ci) * 128 + (ql * 4 + w)) * 64;
#pragma unroll
    for (int g = 0; g < 4; ++g) {
        ushort4 oA, oB;
        oA.x = (ushort)bf16rne(accA[4 * g + 0] * inv);
        oA.y = (ushort)bf16rne(accA[4 * g + 1] * inv);
        oA.z = (ushort)bf16rne(accA[4 * g + 2] * inv);
        oA.w = (ushort)bf16rne(accA[4 * g + 3] * inv);
        oB.x = (ushort)bf16rne(accB[4 * g + 0] * inv);
        oB.y = (ushort)bf16rne(accB[4 * g + 1] * inv);
        oB.z = (ushort)bf16rne(accB[4 * g + 2] * inv);
        oB.w = (ushort)bf16rne(accB[4 * g + 3] * inv);
        *reinterpret_cast<ushort4*>(&crow_[g * 8 + hi * 4])      = oA;
        *reinterpret_cast<ushort4*>(&crow_[g * 8 + hi * 4 + 32]) = oB;
    }
    if (hi == 0) {
        float2 v; v.x = mrow; v.y = lrow;
        ml[(size_t)(bh * 16 + ci) * 128 + ql * 4 + w] = v;
    }
}

// ---------------------------------------------------------------------------
// Merge chunk partials (1..4 per q-row): out = sum_c w_c * o_c.
// ---------------------------------------------------------------------------
__global__ __launch_bounds__(256) void attn_merge(
    const ushort* __restrict__ ctxP, const float2* __restrict__ ml,
    ushort* __restrict__ ctx)
{
    const size_t idx = ((size_t)blockIdx.x * 256 + threadIdx.x) * 8;
    const int col = (int)(idx & 1023);
    const int row = (int)(idx >> 10);
    const int b = row >> 10, s = row & 1023;
    const int h = col >> 6, dk0 = col & 63;
    const int bh = b * 16 + h;
    const int qb = s >> 7, rl = s & 127;
    const int nch = (int)((NCHPACK >> (qb * 4)) & 15);
    const int cb  = (int)((CBPACK >> (qb * 8)) & 255);

    float mm[4], ll[4];
    float m = -1e30f;
#pragma unroll
    for (int c = 0; c < 4; ++c)
        if (c < nch) {
            const float2 v = ml[(size_t)(bh * 16 + cb + c) * 128 + rl];
            mm[c] = v.x; ll[c] = v.y;
            m = fmaxf(m, v.x);
        }
    float wc[4], wsum = 0.f;
#pragma unroll
    for (int c = 0; c < 4; ++c)
        if (c < nch) { wc[c] = ll[c] * __expf(mm[c] - m); wsum += wc[c]; }
    const float inv = (wsum > 0.f) ? 1.f / wsum : 0.f;

    float o[8] = {0.f, 0.f, 0.f, 0.f, 0.f, 0.f, 0.f, 0.f};
#pragma unroll
    for (int c = 0; c < 4; ++c)
        if (c < nch) {
            union { int4 v; ushort u[8]; } p;
            p.v = *reinterpret_cast<const int4*>(
                &ctxP[((size_t)(bh * 16 + cb + c) * 128 + rl) * 64 + dk0]);
            const float wgt = wc[c] * inv;
#pragma unroll
            for (int i = 0; i < 8; ++i)
                o[i] += wgt * __uint_as_float((unsigned)p.u[i] << 16);
        }
    union { int4 v; ushort u[8]; } r;
#pragma unroll
    for (int i = 0; i < 8; ++i) r.u[i] = (ushort)bf16rne(o[i]);
    *reinterpret_cast<int4*>(ctx + idx) = r.v;
}

// ---------------------------------------------------------------------------
// LayerNorm over last dim (1024).
// ---------------------------------------------------------------------------
__global__ __launch_bounds__(256) void layernorm_k(
    const float* __restrict__ x, const float* __restrict__ gamma,
    const float* __restrict__ beta, float* __restrict__ out)
{
    const int row = blockIdx.x;
    const int t   = threadIdx.x;
    const float4 v = *reinterpret_cast<const float4*>(&x[(size_t)row * D_ + (t << 2)]);
    float sum = v.x + v.y + v.z + v.w;
    float sq  = v.x * v.x + v.y * v.y + v.z * v.z + v.w * v.w;
#pragma unroll
    for (int w = 1; w < 64; w <<= 1) {
        sum += __shfl_xor(sum, w, 64);
        sq  += __shfl_xor(sq,  w, 64);
    }
    __shared__ float red[8];
    const int wid = t >> 6;
    if ((t & 63) == 0) { red[wid] = sum; red[wid + 4] = sq; }
    __syncthreads();
    sum = red[0] + red[1] + red[2] + red[3];
    sq  = red[4] + red[5] + red[6] + red[7];
    const float mu  = sum * (1.f / 1024.f);
    const float var = sq * (1.f / 1024.f) - mu * mu;
    const float rs  = rsqrtf(var + 1e-5f);
    const float4 gm = *reinterpret_cast<const float4*>(&gamma[t << 2]);
    const float4 bt = *reinterpret_cast<const float4*>(&beta[t << 2]);
    float4 o;
    o.x = (v.x - mu) * rs * gm.x + bt.x;
    o.y = (v.y - mu) * rs * gm.y + bt.y;
    o.z = (v.z - mu) * rs * gm.z + bt.z;
    o.w = (v.w - mu) * rs * gm.w + bt.w;
    *reinterpret_cast<float4*>(&out[(size_t)row * D_ + (t << 2)]) = o;
}

// ---------------------------------------------------------------------------
extern "C" void kernel_launch(void* const* d_in, const int* in_sizes, int n_in,
                              void* d_out, int out_size, void* d_ws, size_t ws_size,
                              hipStream_t stream)
{
    const float* query  = (const float*)d_in[0];
    const float* key    = (const float*)d_in[1];
    const float* values = (const float*)d_in[2];
    const float* SW     = (const float*)d_in[4];
    const float* Wq     = (const float*)d_in[5];
    const float* bq     = (const float*)d_in[6];
    const float* Wv     = (const float*)d_in[7];
    const float* bv     = (const float*)d_in[8];
    const float* Wo     = (const float*)d_in[9];
    const float* bo     = (const float*)d_in[10];
    const float* gamma  = (const float*)d_in[11];
    const float* beta   = (const float*)d_in[12];

    char* ws = (char*)d_ws;
    const size_t MB = 1024 * 1024;
    ushort* Qh   = (ushort*)(ws);              //  8 MB bf16 [bh][S][DK] (pre-scaled 1/8)
    ushort* Kh   = (ushort*)(ws +  8 * MB);
    ushort* Vt   = (ushort*)(ws + 16 * MB);    //  8 MB bf16 [bh][DK][S]
    ushort* Wqt  = (ushort*)(ws + 24 * MB);    //  2 MB each
    ushort* Wvt  = (ushort*)(ws + 26 * MB);
    ushort* Wot  = (ushort*)(ws + 28 * MB);
    ushort* ctxP = (ushort*)(ws + 30 * MB);    // 16 MB partials (30..46)
    float2* ml   = (float2*)(ws + 46 * MB);    //  1 MB
    ushort* ctxm = Qh;                         //  8 MB merged, overlays Qh (dead post-attn)
    float*  xbf  = (float*)(ws + 8 * MB);      // 16 MB fp32, overlays Kh|Vt (dead post-attn)

    const dim3 blk(256);

    transpose_cvt3<<<dim3(32, 32, 3), blk, 0, stream>>>(Wq, Wv, Wo, Wqt, Wvt, Wot);

    gemm_qkv<<<dim3(1536), blk, 0, stream>>>(query, key, values, Wqt, Wvt,
                                             bq, bv, Qh, Kh, Vt);

    attn_mfma<<<dim3(1024), blk, 0, stream>>>(Qh, Kh, Vt, SW, ctxP, ml);
    attn_merge<<<dim3(2048), blk, 0, stream>>>(ctxP, ml, ctxm);

    gemm_bf16a<<<dim3(512), blk, 0, stream>>>(ctxm, Wot, bo, query, xbf);

    layernorm_k<<<dim3(4096), blk, 0, stream>>>(xbf, gamma, beta, (float*)d_out);
}